// Round 1
// baseline (855.613 us; speedup 1.0000x reference)
//
#include <hip/hip_runtime.h>
#include <cfloat>

#define B_ 8
#define C_ 64
#define N_ 4096
#define K_ 20

// ws layout:
//   xx : 32768 floats                     (128 KB)
//   idx: 32768*20 ints                    (2.56 MB)
//   qg : 8*4096*128 floats [b][m][o2]     (16 MB)   o2<64: q=W1.x  o2>=64: g=(W2-W1).x
#define XX_ELE   (B_ * N_)
#define IDX_ELE  (B_ * N_ * K_)

// ---------------- Kernel 1: xx[b][n] = sum_c x[b][c][n]^2 ----------------
__global__ __launch_bounds__(256) void k_norms(const float* __restrict__ x,
                                               float* __restrict__ xx) {
    int gid = blockIdx.x * 256 + threadIdx.x;       // 0..32767
    int b = gid >> 12, n = gid & (N_ - 1);
    const float* xp = x + (size_t)b * C_ * N_ + n;
    float s = 0.f;
#pragma unroll 8
    for (int c = 0; c < C_; ++c) { float v = xp[(size_t)c * N_]; s += v * v; }
    xx[gid] = s;
}

// ---------------- Kernel 2: fused gram + per-row top-20 -> idx ----------------
// block: 256 thr = 64 rows x 4 m-quadrants. grid: 512 (b = blk&7 for XCD-local L2)
__global__ __launch_bounds__(256) void k_topk(const float* __restrict__ x,
                                              const float* __restrict__ xx,
                                              int* __restrict__ idxo) {
    __shared__ float sm[10240];          // 40 KB; phase1: xc(4096)+xm(4096)+xxs(64); phase2: mval/mind
    float* xc  = sm;                     // [c][r]  64x64
    float* xm  = sm + 4096;              // [g][c][j] 4x64x16
    float* xxs = sm + 8192;              // [g][j] 4x16

    int b = blockIdx.x & 7, nt = blockIdx.x >> 3;
    int n0 = nt * 64;
    int tid = threadIdx.x;
    int r = tid & 63, g = tid >> 6;
    const float* xb = x + (size_t)b * C_ * N_;

    // stage centers xc[c][r] = x[b][c][n0+r]
#pragma unroll
    for (int i = 0; i < 4; ++i) {
        int lin = tid + 256 * i;         // 0..1023
        int c = lin >> 4, f = lin & 15;
        *(float4*)&xc[c * 64 + f * 4] =
            *(const float4*)&xb[(size_t)c * N_ + n0 + f * 4];
    }

    float val[20]; int ind[20];
#pragma unroll
    for (int j = 0; j < 20; ++j) { val[j] = -FLT_MAX; ind[j] = 0; }

    for (int step = 0; step < 64; ++step) {
        int m0 = step * 16;
        __syncthreads();
        // stage xm[g][c][j] = x[b][c][g*1024 + m0 + j]
#pragma unroll
        for (int i = 0; i < 4; ++i) {
            int lin = tid + 256 * i;     // 0..1023
            int gc = lin >> 2, jf = lin & 3;
            int c = gc & 63, g2 = gc >> 6;
            *(float4*)&xm[(g2 * 64 + c) * 16 + jf * 4] =
                *(const float4*)&xb[(size_t)c * N_ + g2 * 1024 + m0 + jf * 4];
        }
        if (tid < 64) xxs[tid] = xx[b * N_ + (tid >> 4) * 1024 + m0 + (tid & 15)];
        __syncthreads();

        float acc[16];
#pragma unroll
        for (int j = 0; j < 16; ++j) acc[j] = 0.f;
        const float* xmg = xm + g * 1024;
#pragma unroll 4
        for (int c = 0; c < 64; ++c) {
            float a = xc[c * 64 + r];
            const float4* xr4 = (const float4*)&xmg[c * 16];
            float4 v0 = xr4[0], v1 = xr4[1], v2 = xr4[2], v3 = xr4[3];
            float xv[16];
            xv[0]=v0.x; xv[1]=v0.y; xv[2]=v0.z; xv[3]=v0.w;
            xv[4]=v1.x; xv[5]=v1.y; xv[6]=v1.z; xv[7]=v1.w;
            xv[8]=v2.x; xv[9]=v2.y; xv[10]=v2.z; xv[11]=v2.w;
            xv[12]=v3.x; xv[13]=v3.y; xv[14]=v3.z; xv[15]=v3.w;
#pragma unroll
            for (int j = 0; j < 16; ++j) acc[j] += a * xv[j];
        }
        // scores: 2*inner - xx_m  (xx_n constant per row -> same ordering as ref)
        int base = g * 1024 + m0;
#pragma unroll
        for (int j = 0; j < 16; ++j) acc[j] = 2.f * acc[j] - xxs[g * 16 + j];

        float vmin = val[19];
        while (true) {
            float bmax = acc[0]; int bpos = 0;
#pragma unroll
            for (int j = 1; j < 16; ++j) {
                bool cnd = acc[j] > bmax;
                bmax = cnd ? acc[j] : bmax;
                bpos = cnd ? j : bpos;
            }
            bool insv = bmax > vmin;
            if (!__any(insv)) break;
            if (insv) {
                int mi = base + bpos;
                // branchless sorted insert (val descending)
#pragma unroll
                for (int j = 19; j >= 1; --j) {
                    bool c0 = bmax > val[j];
                    bool c1 = bmax > val[j - 1];
                    float nv = c1 ? val[j - 1] : bmax;
                    int   ni = c1 ? ind[j - 1] : mi;
                    val[j] = c0 ? nv : val[j];
                    ind[j] = c0 ? ni : ind[j];
                }
                {
                    bool c0 = bmax > val[0];
                    val[0] = c0 ? bmax : val[0];
                    ind[0] = c0 ? mi : ind[0];
                }
                vmin = val[19];
#pragma unroll
                for (int j = 0; j < 16; ++j) if (j == bpos) acc[j] = -FLT_MAX;
            }
        }
    }

    // ---- merge 4 quadrant lists per row ----
    __syncthreads();
    float* mval = sm;                    // [g][r][k] 5120 floats
    int*   mind = (int*)(sm + 5120);     // 5120 ints
#pragma unroll
    for (int j = 0; j < 20; ++j) {
        mval[tid * 20 + j] = val[j];
        mind[tid * 20 + j] = ind[j];
    }
    __syncthreads();
    if (tid < 64) {
        int p0 = 0, p1 = 0, p2 = 0, p3 = 0;
        int b0 = (0 * 64 + tid) * 20, b1 = (1 * 64 + tid) * 20;
        int b2 = (2 * 64 + tid) * 20, b3 = (3 * 64 + tid) * 20;
        int* op = idxo + ((size_t)b * N_ + n0 + tid) * K_;
        for (int k = 0; k < K_; ++k) {
            float v0 = (p0 < 20) ? mval[b0 + p0] : -FLT_MAX;
            float v1 = (p1 < 20) ? mval[b1 + p1] : -FLT_MAX;
            float v2 = (p2 < 20) ? mval[b2 + p2] : -FLT_MAX;
            float v3 = (p3 < 20) ? mval[b3 + p3] : -FLT_MAX;
            float bv = v0; int bg = 0;
            if (v1 > bv) { bv = v1; bg = 1; }
            if (v2 > bv) { bv = v2; bg = 2; }
            if (v3 > bv) { bv = v3; bg = 3; }
            int pb = (bg == 0) ? p0 : (bg == 1) ? p1 : (bg == 2) ? p2 : p3;
            int bb = (bg == 0) ? b0 : (bg == 1) ? b1 : (bg == 2) ? b2 : b3;
            op[k] = mind[bb + pb];
            p0 += (bg == 0); p1 += (bg == 1); p2 += (bg == 2); p3 += (bg == 3);
        }
    }
}

// ---------------- Kernel 3: qg[b][m][o2] ----------------
// o2<64 : q = sum_c W[o2][c]*x[b][c][m]
// o2>=64: g = sum_c (W[o][64+c]-W[o][c])*x[b][c][m],  o = o2-64
__global__ __launch_bounds__(256) void k_qg(const float* __restrict__ x,
                                            const float* __restrict__ W,
                                            float* __restrict__ qg) {
    __shared__ float Wl[64 * 129];       // [c][o2], pad 129
    __shared__ float xs[64 * 64];        // [c][j]
    int b = blockIdx.x & 7, mt = blockIdx.x >> 3;
    int mbase = mt * 64;
    int tid = threadIdx.x;

    for (int i = 0; i < 32; ++i) {
        int lin = tid + 256 * i;         // 0..8191
        int c = lin & 63, o2 = lin >> 6;
        float wv;
        if (o2 < 64) wv = W[o2 * 128 + c];
        else { int o = o2 - 64; wv = W[o * 128 + 64 + c] - W[o * 128 + c]; }
        Wl[c * 129 + o2] = wv;
    }
#pragma unroll
    for (int i = 0; i < 4; ++i) {
        int lin = tid + 256 * i;
        int c = lin >> 4, f = lin & 15;
        *(float4*)&xs[c * 64 + f * 4] =
            *(const float4*)&x[((size_t)b * C_ + c) * N_ + mbase + f * 4];
    }
    __syncthreads();

    int u = tid & 63, half = tid >> 6;   // o2 in {2u,2u+1}; j in [half*16, half*16+16)
    float a0[16], a1[16];
#pragma unroll
    for (int j = 0; j < 16; ++j) { a0[j] = 0.f; a1[j] = 0.f; }
#pragma unroll 4
    for (int c = 0; c < 64; ++c) {
        float2 wv = *(const float2*)&Wl[c * 129 + 2 * u];
        const float4* xr = (const float4*)&xs[c * 64 + half * 16];
        float4 v0 = xr[0], v1 = xr[1], v2 = xr[2], v3 = xr[3];
        float xv[16];
        xv[0]=v0.x; xv[1]=v0.y; xv[2]=v0.z; xv[3]=v0.w;
        xv[4]=v1.x; xv[5]=v1.y; xv[6]=v1.z; xv[7]=v1.w;
        xv[8]=v2.x; xv[9]=v2.y; xv[10]=v2.z; xv[11]=v2.w;
        xv[12]=v3.x; xv[13]=v3.y; xv[14]=v3.z; xv[15]=v3.w;
#pragma unroll
        for (int j = 0; j < 16; ++j) { a0[j] += wv.x * xv[j]; a1[j] += wv.y * xv[j]; }
    }
#pragma unroll
    for (int j = 0; j < 16; ++j) {
        int m = mbase + half * 16 + j;
        float2 o; o.x = a0[j]; o.y = a1[j];
        *(float2*)&qg[((size_t)b * N_ + m) * 128 + 2 * u] = o;
    }
}

// ---------------- Kernel 4: out[b][o][n] = max_k leaky(q[ik][o] + g[n][o]) ----------------
__global__ __launch_bounds__(256) void k_out(const float* __restrict__ qg,
                                             const int* __restrict__ idxi,
                                             float* __restrict__ out) {
    __shared__ float T[64][65];
    int b = blockIdx.x & 7, nt = blockIdx.x >> 3;
    int n0 = nt * 64;
    int tid = threadIdx.x;
    int w = tid >> 6, o = tid & 63;
    const float* qgb = qg + (size_t)b * N_ * 128;
    for (int i = 0; i < 16; ++i) {
        int nl = w * 16 + i;
        int n = n0 + nl;
        float gv = qgb[(size_t)n * 128 + 64 + o];
        const int* ip = idxi + ((size_t)b * N_ + n) * K_;
        float mx = -FLT_MAX;
#pragma unroll 5
        for (int k = 0; k < K_; ++k) {
            int ik = ip[k];
            float h = qgb[(size_t)ik * 128 + o] + gv;
            h = (h >= 0.f) ? h : 0.01f * h;
            mx = fmaxf(mx, h);
        }
        T[nl][o] = mx;
    }
    __syncthreads();
    int ow = tid >> 2, q = tid & 3;
#pragma unroll
    for (int j4 = 0; j4 < 4; ++j4) {
        int nl = q * 16 + j4 * 4;
        float4 v;
        v.x = T[nl + 0][ow]; v.y = T[nl + 1][ow];
        v.z = T[nl + 2][ow]; v.w = T[nl + 3][ow];
        *(float4*)&out[((size_t)b * 64 + ow) * N_ + n0 + nl] = v;
    }
}

extern "C" void kernel_launch(void* const* d_in, const int* in_sizes, int n_in,
                              void* d_out, int out_size, void* d_ws, size_t ws_size,
                              hipStream_t stream) {
    const float* x = (const float*)d_in[0];
    const float* W = (const float*)d_in[1];
    float* out = (float*)d_out;

    float* xx  = (float*)d_ws;
    int*   idx = (int*)((char*)d_ws + (size_t)XX_ELE * 4);
    float* qg  = (float*)((char*)d_ws + (size_t)XX_ELE * 4 + (size_t)IDX_ELE * 4);

    k_norms<<<dim3(B_ * N_ / 256), dim3(256), 0, stream>>>(x, xx);
    k_qg   <<<dim3(512), dim3(256), 0, stream>>>(x, W, qg);
    k_topk <<<dim3(512), dim3(256), 0, stream>>>(x, xx, idx);
    k_out  <<<dim3(512), dim3(256), 0, stream>>>(qg, idx, out);
}

// Round 3
// 493.605 us; speedup vs baseline: 1.7334x; 1.7334x over previous
//
#include <hip/hip_runtime.h>
#include <cfloat>

#define B_ 8
#define C_ 64
#define N_ 4096
#define K_ 20

typedef float f32x4v  __attribute__((ext_vector_type(4)));
typedef float f32x16v __attribute__((ext_vector_type(16)));
typedef _Float16 f16x8 __attribute__((ext_vector_type(8)));

// ws layout (bytes):
//   xxh : B*N floats (= xx/2, fp64-accumulated)     @ 0         (131072)
//   idx : B*N*20 ints                               @ 131072    (2621440)
//   qg  : B*N*128 floats [b][m][o2]                 @ 2752512   (16777216)
//   P0  : [b][seg][m][j] f16 limb0                  @ 19529728  (4194304)
//   P1  : limb1 (scale 2^-12)                       @ 23724032  (4194304)
//   P2  : limb2 (scale 2^-24)                       @ 27918336  (4194304)
#define OFF_IDX 131072
#define OFF_QG  2752512
#define OFF_P0  19529728
#define OFF_P1  23724032
#define OFF_P2  27918336

// ---------------- Kernel 1: exact 3-limb fp16 split + xx/2 (fp64 acc) ----------------
__global__ __launch_bounds__(256) void k_split(const float* __restrict__ x,
                                               unsigned short* __restrict__ p0,
                                               unsigned short* __restrict__ p1,
                                               unsigned short* __restrict__ p2,
                                               float* __restrict__ xxh) {
    int b = blockIdx.x & 7, mt = blockIdx.x >> 3;
    int m = mt * 256 + threadIdx.x;
    const float* xb = x + (size_t)b * C_ * N_;
    double ss = 0.0;
#pragma unroll 1
    for (int seg = 0; seg < 8; ++seg) {
        unsigned short h0[8], h1[8], h2[8];
#pragma unroll
        for (int j = 0; j < 8; ++j) {
            float v = xb[(size_t)(seg * 8 + j) * N_ + m];
            ss += (double)v * (double)v;
            _Float16 a = (_Float16)v;                       // RNE
            float r = v - (float)a;                         // exact
            _Float16 bq = (_Float16)(r * 4096.f);           // limb1 * 2^12
            float r2 = r - (float)bq * (1.f / 4096.f);      // exact (Sterbenz)
            _Float16 cq = (_Float16)(r2 * 16777216.f);      // limb2 * 2^24, exact
            h0[j] = __builtin_bit_cast(unsigned short, a);
            h1[j] = __builtin_bit_cast(unsigned short, bq);
            h2[j] = __builtin_bit_cast(unsigned short, cq);
        }
        uint4 q0, q1, q2;
        q0.x = h0[0] | (h0[1] << 16); q0.y = h0[2] | (h0[3] << 16);
        q0.z = h0[4] | (h0[5] << 16); q0.w = h0[6] | (h0[7] << 16);
        q1.x = h1[0] | (h1[1] << 16); q1.y = h1[2] | (h1[3] << 16);
        q1.z = h1[4] | (h1[5] << 16); q1.w = h1[6] | (h1[7] << 16);
        q2.x = h2[0] | (h2[1] << 16); q2.y = h2[2] | (h2[3] << 16);
        q2.z = h2[4] | (h2[5] << 16); q2.w = h2[6] | (h2[7] << 16);
        size_t o16 = (size_t)(b * 8 + seg) * N_ + m;
        ((uint4*)p0)[o16] = q0;
        ((uint4*)p1)[o16] = q1;
        ((uint4*)p2)[o16] = q2;
    }
    xxh[b * N_ + m] = (float)(0.5 * ss);
}

// ---------------- Kernel 2: MFMA gram (exact split) + per-row top-20 ----------------
// grid 256 = 8 b x 32 n-tiles(128 rows). block 256 = 4 waves, wave = 32 rows.
// LDS: 3 panels x 8 seg x 256 m x 16B = 96 KB, 16B-stride (conflict-free) + xxs 1KB.
#define MCH 256
__global__ __launch_bounds__(256) void k_topk(const unsigned short* __restrict__ p0g,
                                              const unsigned short* __restrict__ p1g,
                                              const unsigned short* __restrict__ p2g,
                                              const float* __restrict__ xxh,
                                              int* __restrict__ idxo) {
    __shared__ __align__(16) char smem[98304 + 1024];
    int b = blockIdx.x & 7, nt = blockIdx.x >> 3;
    int tid = threadIdx.x;
    int w = tid >> 6, l = tid & 63, h = l >> 5, mf = l & 31;
    int n0w = nt * 128 + w * 32;
    int b8 = b * 8;
    const f32x4v* g0 = (const f32x4v*)p0g;
    const f32x4v* g1 = (const f32x4v*)p1g;
    const f32x4v* g2v = (const f32x4v*)p2g;
    float* xxs = (float*)(smem + 98304);

    // B fragments (center rows), register-resident for the whole kernel
    f16x8 b0[4], b1[4], b2[4];
#pragma unroll
    for (int kc = 0; kc < 4; ++kc) {
        int seg = kc * 2 + h;
        size_t gi = (size_t)(b8 + seg) * N_ + n0w + mf;
        b0[kc] = __builtin_bit_cast(f16x8, g0[gi]);
        b1[kc] = __builtin_bit_cast(f16x8, g1[gi]);
        b2[kc] = __builtin_bit_cast(f16x8, g2v[gi]);
    }

    float val[20]; int ind[20];
#pragma unroll
    for (int j = 0; j < 20; ++j) { val[j] = -FLT_MAX; ind[j] = 0; }

#pragma unroll 1
    for (int ch = 0; ch < N_ / MCH; ++ch) {
        int m0 = ch * MCH;
        __syncthreads();
        // stage chunk: 3 panels, contiguous 16B entries
#pragma unroll
        for (int i = 0; i < 24; ++i) {
            int lin = i * 256 + tid;             // 0..6143
            int pnl = lin >> 11;                 // 0..2 (i/8 at unroll time)
            int rem = lin & 2047;
            int seg = rem >> 8, ml = rem & 255;
            size_t gi = (size_t)(b8 + seg) * N_ + m0 + ml;
            const f32x4v* src = (pnl == 0) ? g0 : (pnl == 1) ? g1 : g2v;
            *(f32x4v*)(smem + pnl * 32768 + seg * 4096 + ml * 16) = src[gi];
        }
        xxs[tid] = xxh[b * N_ + m0 + tid];
        __syncthreads();

#pragma unroll 1
        for (int t = 0; t < 8; ++t) {
            int m0t = t * 32;
            // acc1 init = -xx_m/2 ; acc2, acc3 init 0
            f32x16v acc1, acc2, acc3;
#pragma unroll
            for (int g2i = 0; g2i < 4; ++g2i) {
                f32x4v xv = *(const f32x4v*)&xxs[m0t + 4 * h + 8 * g2i];
#pragma unroll
                for (int q = 0; q < 4; ++q) {
                    acc1[g2i * 4 + q] = -xv[q];
                    acc2[g2i * 4 + q] = 0.f;
                    acc3[g2i * 4 + q] = 0.f;
                }
            }
#pragma unroll
            for (int kc = 0; kc < 4; ++kc) {
                int seg = kc * 2 + h;
                const char* pA = smem + seg * 4096 + (m0t + mf) * 16;
                f16x8 a0 = __builtin_bit_cast(f16x8, *(const f32x4v*)pA);
                f16x8 a1 = __builtin_bit_cast(f16x8, *(const f32x4v*)(pA + 32768));
                f16x8 a2 = __builtin_bit_cast(f16x8, *(const f32x4v*)(pA + 65536));
                acc1 = __builtin_amdgcn_mfma_f32_32x32x16_f16(a0, b0[kc], acc1, 0, 0, 0);
                acc2 = __builtin_amdgcn_mfma_f32_32x32x16_f16(a0, b1[kc], acc2, 0, 0, 0);
                acc2 = __builtin_amdgcn_mfma_f32_32x32x16_f16(a1, b0[kc], acc2, 0, 0, 0);
                acc3 = __builtin_amdgcn_mfma_f32_32x32x16_f16(a1, b1[kc], acc3, 0, 0, 0);
                acc3 = __builtin_amdgcn_mfma_f32_32x32x16_f16(a0, b2[kc], acc3, 0, 0, 0);
                acc3 = __builtin_amdgcn_mfma_f32_32x32x16_f16(a2, b0[kc], acc3, 0, 0, 0);
            }
            // combine scales: s = acc1 + (acc2 + acc3*2^-12)*2^-12
            float s[16];
#pragma unroll
            for (int r = 0; r < 16; ++r)
                s[r] = acc1[r] + (acc2[r] + acc3[r] * (1.f / 4096.f)) * (1.f / 4096.f);

            int base = m0 + m0t + 4 * h;
            float vmin = val[19];
            while (true) {
                float bmax = s[0]; int bpos = 0;
#pragma unroll
                for (int r = 1; r < 16; ++r) {
                    bool c = s[r] > bmax;
                    bmax = c ? s[r] : bmax;
                    bpos = c ? r : bpos;
                }
                bool insv = bmax > vmin;
                if (!__any(insv)) break;
                if (insv) {
                    int mi = base + (bpos & 3) + 8 * (bpos >> 2);
#pragma unroll
                    for (int j = 19; j >= 1; --j) {
                        bool c0 = bmax > val[j];
                        bool c1 = bmax > val[j - 1];
                        float nv = c1 ? val[j - 1] : bmax;
                        int   ni = c1 ? ind[j - 1] : mi;
                        val[j] = c0 ? nv : val[j];
                        ind[j] = c0 ? ni : ind[j];
                    }
                    {
                        bool c0 = bmax > val[0];
                        val[0] = c0 ? bmax : val[0];
                        ind[0] = c0 ? mi : ind[0];
                    }
                    vmin = val[19];
#pragma unroll
                    for (int r = 0; r < 16; ++r) if (r == bpos) s[r] = -FLT_MAX;
                }
            }
        }
    }

    // ---- merge the two half-lists per row (lanes l and l+32) ----
    __syncthreads();
    {
        float* mv = (float*)(smem + w * 10240 + l * 160);
        int*   mi2 = (int*)(smem + w * 10240 + l * 160 + 80);
#pragma unroll
        for (int j = 0; j < 20; ++j) { mv[j] = val[j]; mi2[j] = ind[j]; }
    }
    __syncthreads();
    if (h == 0) {
        const float* va = (const float*)(smem + w * 10240 + l * 160);
        const int*   ia = (const int*)(smem + w * 10240 + l * 160 + 80);
        const float* vb = (const float*)(smem + w * 10240 + (l + 32) * 160);
        const int*   ib = (const int*)(smem + w * 10240 + (l + 32) * 160 + 80);
        int p = 0, q = 0;
        int* op = idxo + ((size_t)b * N_ + n0w + l) * K_;
        for (int k = 0; k < K_; ++k) {
            float fa = va[p], fb = vb[q];
            bool ta = fa >= fb;
            op[k] = ta ? ia[p] : ib[q];
            p += ta; q += !ta;
        }
    }
}

// ---------------- Kernel 3: qg[b][m][o2] ----------------
__global__ __launch_bounds__(256) void k_qg(const float* __restrict__ x,
                                            const float* __restrict__ W,
                                            float* __restrict__ qg) {
    __shared__ float Wl[64 * 129];
    __shared__ float xs[64 * 64];
    int b = blockIdx.x & 7, mt = blockIdx.x >> 3;
    int mbase = mt * 64;
    int tid = threadIdx.x;

    for (int i = 0; i < 32; ++i) {
        int lin = tid + 256 * i;
        int c = lin & 63, o2 = lin >> 6;
        float wv;
        if (o2 < 64) wv = W[o2 * 128 + c];
        else { int o = o2 - 64; wv = W[o * 128 + 64 + c] - W[o * 128 + c]; }
        Wl[c * 129 + o2] = wv;
    }
#pragma unroll
    for (int i = 0; i < 4; ++i) {
        int lin = tid + 256 * i;
        int c = lin >> 4, f = lin & 15;
        *(float4*)&xs[c * 64 + f * 4] =
            *(const float4*)&x[((size_t)b * C_ + c) * N_ + mbase + f * 4];
    }
    __syncthreads();

    int u = tid & 63, half = tid >> 6;
    float a0[16], a1[16];
#pragma unroll
    for (int j = 0; j < 16; ++j) { a0[j] = 0.f; a1[j] = 0.f; }
#pragma unroll 4
    for (int c = 0; c < 64; ++c) {
        float2 wv = *(const float2*)&Wl[c * 129 + 2 * u];
        const float4* xr = (const float4*)&xs[c * 64 + half * 16];
        float4 v0 = xr[0], v1 = xr[1], v2 = xr[2], v3 = xr[3];
        float xvv[16];
        xvv[0]=v0.x; xvv[1]=v0.y; xvv[2]=v0.z; xvv[3]=v0.w;
        xvv[4]=v1.x; xvv[5]=v1.y; xvv[6]=v1.z; xvv[7]=v1.w;
        xvv[8]=v2.x; xvv[9]=v2.y; xvv[10]=v2.z; xvv[11]=v2.w;
        xvv[12]=v3.x; xvv[13]=v3.y; xvv[14]=v3.z; xvv[15]=v3.w;
#pragma unroll
        for (int j = 0; j < 16; ++j) { a0[j] += wv.x * xvv[j]; a1[j] += wv.y * xvv[j]; }
    }
#pragma unroll
    for (int j = 0; j < 16; ++j) {
        int m = mbase + half * 16 + j;
        float2 o; o.x = a0[j]; o.y = a1[j];
        *(float2*)&qg[((size_t)b * N_ + m) * 128 + 2 * u] = o;
    }
}

// ---------------- Kernel 4: out = max_k leaky(q[ik][o] + g[n][o]) ----------------
__global__ __launch_bounds__(256) void k_out(const float* __restrict__ qg,
                                             const int* __restrict__ idxi,
                                             float* __restrict__ out) {
    __shared__ float T[64][65];
    int b = blockIdx.x & 7, nt = blockIdx.x >> 3;
    int n0 = nt * 64;
    int tid = threadIdx.x;
    int w = tid >> 6, o = tid & 63;
    const float* qgb = qg + (size_t)b * N_ * 128;
    for (int i = 0; i < 16; ++i) {
        int nl = w * 16 + i;
        int n = n0 + nl;
        float gv = qgb[(size_t)n * 128 + 64 + o];
        const int* ip = idxi + ((size_t)b * N_ + n) * K_;
        float mx = -FLT_MAX;
#pragma unroll 5
        for (int k = 0; k < K_; ++k) {
            int ik = ip[k];
            float hh = qgb[(size_t)ik * 128 + o] + gv;
            hh = (hh >= 0.f) ? hh : 0.01f * hh;
            mx = fmaxf(mx, hh);
        }
        T[nl][o] = mx;
    }
    __syncthreads();
    int ow = tid >> 2, q = tid & 3;
#pragma unroll
    for (int j4 = 0; j4 < 4; ++j4) {
        int nl = q * 16 + j4 * 4;
        float4 v;
        v.x = T[nl + 0][ow]; v.y = T[nl + 1][ow];
        v.z = T[nl + 2][ow]; v.w = T[nl + 3][ow];
        *(float4*)&out[((size_t)b * 64 + ow) * N_ + n0 + nl] = v;
    }
}

extern "C" void kernel_launch(void* const* d_in, const int* in_sizes, int n_in,
                              void* d_out, int out_size, void* d_ws, size_t ws_size,
                              hipStream_t stream) {
    const float* x = (const float*)d_in[0];
    const float* W = (const float*)d_in[1];
    float* out = (float*)d_out;

    float*          xxh = (float*)d_ws;
    int*            idx = (int*)((char*)d_ws + OFF_IDX);
    float*          qg  = (float*)((char*)d_ws + OFF_QG);
    unsigned short* p0  = (unsigned short*)((char*)d_ws + OFF_P0);
    unsigned short* p1  = (unsigned short*)((char*)d_ws + OFF_P1);
    unsigned short* p2  = (unsigned short*)((char*)d_ws + OFF_P2);

    k_split<<<dim3(128), dim3(256), 0, stream>>>(x, p0, p1, p2, xxh);
    k_qg   <<<dim3(512), dim3(256), 0, stream>>>(x, W, qg);
    k_topk <<<dim3(256), dim3(256), 0, stream>>>(p0, p1, p2, xxh, idx);
    k_out  <<<dim3(512), dim3(256), 0, stream>>>(qg, idx, out);
}

// Round 4
// 462.806 us; speedup vs baseline: 1.8487x; 1.0665x over previous
//
#include <hip/hip_runtime.h>
#include <cfloat>

#define B_ 8
#define C_ 64
#define N_ 4096
#define K_ 20

typedef float f32x4v  __attribute__((ext_vector_type(4)));
typedef float f32x16v __attribute__((ext_vector_type(16)));
typedef _Float16 f16x8 __attribute__((ext_vector_type(8)));
typedef unsigned long long u64;

// ws layout (bytes) — same as round 3 (proven to fit):
#define OFF_IDX 131072
#define OFF_QG  2752512
#define OFF_P0  19529728
#define OFF_P1  23724032
#define OFF_P2  27918336

// ---------------- Kernel 1: exact 3-limb fp16 split + xx/2 (fp64 acc) ----------------
__global__ __launch_bounds__(256) void k_split(const float* __restrict__ x,
                                               unsigned short* __restrict__ p0,
                                               unsigned short* __restrict__ p1,
                                               unsigned short* __restrict__ p2,
                                               float* __restrict__ xxh) {
    int b = blockIdx.x & 7, mt = blockIdx.x >> 3;
    int m = mt * 256 + threadIdx.x;
    const float* xb = x + (size_t)b * C_ * N_;
    double ss = 0.0;
#pragma unroll 1
    for (int seg = 0; seg < 8; ++seg) {
        unsigned short h0[8], h1[8], h2[8];
#pragma unroll
        for (int j = 0; j < 8; ++j) {
            float v = xb[(size_t)(seg * 8 + j) * N_ + m];
            ss += (double)v * (double)v;
            _Float16 a = (_Float16)v;
            float r = v - (float)a;
            _Float16 bq = (_Float16)(r * 4096.f);
            float r2 = r - (float)bq * (1.f / 4096.f);
            _Float16 cq = (_Float16)(r2 * 16777216.f);
            h0[j] = __builtin_bit_cast(unsigned short, a);
            h1[j] = __builtin_bit_cast(unsigned short, bq);
            h2[j] = __builtin_bit_cast(unsigned short, cq);
        }
        uint4 q0, q1, q2;
        q0.x = h0[0] | (h0[1] << 16); q0.y = h0[2] | (h0[3] << 16);
        q0.z = h0[4] | (h0[5] << 16); q0.w = h0[6] | (h0[7] << 16);
        q1.x = h1[0] | (h1[1] << 16); q1.y = h1[2] | (h1[3] << 16);
        q1.z = h1[4] | (h1[5] << 16); q1.w = h1[6] | (h1[7] << 16);
        q2.x = h2[0] | (h2[1] << 16); q2.y = h2[2] | (h2[3] << 16);
        q2.z = h2[4] | (h2[5] << 16); q2.w = h2[6] | (h2[7] << 16);
        size_t o16 = (size_t)(b * 8 + seg) * N_ + m;
        ((uint4*)p0)[o16] = q0;
        ((uint4*)p1)[o16] = q1;
        ((uint4*)p2)[o16] = q2;
    }
    xxh[b * N_ + m] = (float)(0.5 * ss);
}

// ---------------- Kernel 2: MFMA gram + top-20, candidate-split waves ----------------
// grid 256 = 8b x 32nt (128 rows). block 512 = 8 waves: wg=w&3 rows, cs=w>>2 scans
// candidates [cs*2048, cs*2048+2048) in 8 chunks of 256. 2 LDS panels (P0,P1).
__global__ __launch_bounds__(512, 2) void k_topk(const unsigned short* __restrict__ p0g,
                                                 const unsigned short* __restrict__ p1g,
                                                 const unsigned short* __restrict__ p2g,
                                                 const float* __restrict__ xxh,
                                                 int* __restrict__ idxo) {
    __shared__ __align__(16) char smem[133120];  // staging 128K + xxs 2K; merge reuses 87K
    int b = blockIdx.x & 7, nt = blockIdx.x >> 3;
    int n0 = nt * 128;
    int tid = threadIdx.x;
    int w = tid >> 6, l = tid & 63, h = l >> 5, mf = l & 31;
    int cs = w >> 2, wg = w & 3, tig = tid & 255;
    int b8 = b * 8;
    const f32x4v* g0 = (const f32x4v*)p0g;
    const f32x4v* g1 = (const f32x4v*)p1g;
    const f32x4v* g2v = (const f32x4v*)p2g;
    float* xxs = (float*)(smem + 131072);
    const float c12 = 1.f / 4096.f;

    // B fragments (center rows n0 + wg*32 + mf), 3 limbs, register-resident
    f16x8 b0[4], b1[4], b2[4];
#pragma unroll
    for (int kc = 0; kc < 4; ++kc) {
        int seg = kc * 2 + h;
        size_t gi = (size_t)(b8 + seg) * N_ + n0 + wg * 32 + mf;
        b0[kc] = __builtin_bit_cast(f16x8, g0[gi]);
        b1[kc] = __builtin_bit_cast(f16x8, g1[gi]);
        b2[kc] = __builtin_bit_cast(f16x8, g2v[gi]);
    }

    float val[20]; int ind[20];
#pragma unroll
    for (int j = 0; j < 20; ++j) { val[j] = -FLT_MAX; ind[j] = 0; }

#pragma unroll 1
    for (int ch = 0; ch < 8; ++ch) {
        int cb = cs * 2048 + ch * 256;           // candidate base for this cs-group
        __syncthreads();
        // stage 2 panels x 8 seg x 256 cand (per cs-group: 256 threads, 16 iters)
#pragma unroll
        for (int i = 0; i < 16; ++i) {
            int lin = i * 256 + tig;             // 0..4095
            int panel = lin >> 11;
            int rem = lin & 2047;
            int seg = rem >> 8, ml = rem & 255;
            size_t gi = (size_t)(b8 + seg) * N_ + cb + ml;
            const f32x4v* src = panel ? g1 : g0;
            *(f32x4v*)(smem + cs * 65536 + panel * 32768 + seg * 4096 + ml * 16) = src[gi];
        }
        xxs[cs * 256 + tig] = xxh[b * N_ + cb + tig];
        __syncthreads();

#pragma unroll 1
        for (int t = 0; t < 8; ++t) {
            int m0t = t * 32;
            f32x16v acc1, acc2, acc3;
#pragma unroll
            for (int g2i = 0; g2i < 4; ++g2i) {
                f32x4v xv = *(const f32x4v*)&xxs[cs * 256 + m0t + 4 * h + 8 * g2i];
#pragma unroll
                for (int q = 0; q < 4; ++q) {
                    acc1[g2i * 4 + q] = -xv[q];
                    acc2[g2i * 4 + q] = 0.f;
                    acc3[g2i * 4 + q] = 0.f;
                }
            }
            f16x8 a0[4], a1[4];
#pragma unroll
            for (int kc = 0; kc < 4; ++kc) {
                int seg = kc * 2 + h;
                const char* pA = smem + cs * 65536 + seg * 4096 + (m0t + mf) * 16;
                a0[kc] = __builtin_bit_cast(f16x8, *(const f32x4v*)pA);
                a1[kc] = __builtin_bit_cast(f16x8, *(const f32x4v*)(pA + 32768));
            }
#pragma unroll
            for (int kc = 0; kc < 4; ++kc)
                acc1 = __builtin_amdgcn_mfma_f32_32x32x16_f16(a0[kc], b0[kc], acc1, 0, 0, 0);
#pragma unroll
            for (int kc = 0; kc < 4; ++kc) {
                acc2 = __builtin_amdgcn_mfma_f32_32x32x16_f16(a0[kc], b1[kc], acc2, 0, 0, 0);
                acc2 = __builtin_amdgcn_mfma_f32_32x32x16_f16(a1[kc], b0[kc], acc2, 0, 0, 0);
            }
#pragma unroll
            for (int kc = 0; kc < 4; ++kc) {
                acc3 = __builtin_amdgcn_mfma_f32_32x32x16_f16(a1[kc], b1[kc], acc3, 0, 0, 0);
                acc3 = __builtin_amdgcn_mfma_f32_32x32x16_f16(a0[kc], b2[kc], acc3, 0, 0, 0);
            }
            // s = acc1 + acc2*2^-12 + acc3*2^-24
            float s[16];
#pragma unroll
            for (int r = 0; r < 16; ++r)
                s[r] = acc1[r] + (acc2[r] + acc3[r] * c12) * c12;

            int base = cb + m0t + 4 * h;
            float vmin = val[19];
            // prefilter max-tree
            float m8[8];
#pragma unroll
            for (int r = 0; r < 8; ++r) m8[r] = fmaxf(s[r], s[r + 8]);
            float m4a = fmaxf(m8[0], m8[1]), m4b = fmaxf(m8[2], m8[3]);
            float m4c = fmaxf(m8[4], m8[5]), m4d = fmaxf(m8[6], m8[7]);
            float bmax = fmaxf(fmaxf(m4a, m4b), fmaxf(m4c, m4d));
            while (__any(bmax > vmin)) {
                if (bmax > vmin) {
                    // lowest r with s[r]==bmax (lowest index on ties)
                    int bpos = 15;
#pragma unroll
                    for (int r = 14; r >= 0; --r) bpos = (s[r] == bmax) ? r : bpos;
                    int mi = base + (bpos & 3) + 8 * (bpos >> 2);
                    // sorted insert (descending)
#pragma unroll
                    for (int j = 19; j >= 1; --j) {
                        bool c0 = bmax > val[j];
                        bool c1 = bmax > val[j - 1];
                        float nv = c1 ? val[j - 1] : bmax;
                        int   ni = c1 ? ind[j - 1] : mi;
                        val[j] = c0 ? nv : val[j];
                        ind[j] = c0 ? ni : ind[j];
                    }
                    {
                        bool c0 = bmax > val[0];
                        val[0] = c0 ? bmax : val[0];
                        ind[0] = c0 ? mi : ind[0];
                    }
                    vmin = val[19];
#pragma unroll
                    for (int r = 0; r < 16; ++r) if (r == bpos) s[r] = -FLT_MAX;
                }
#pragma unroll
                for (int r = 0; r < 8; ++r) m8[r] = fmaxf(s[r], s[r + 8]);
                m4a = fmaxf(m8[0], m8[1]); m4b = fmaxf(m8[2], m8[3]);
                m4c = fmaxf(m8[4], m8[5]); m4d = fmaxf(m8[6], m8[7]);
                bmax = fmaxf(fmaxf(m4a, m4b), fmaxf(m4c, m4d));
            }
        }
    }

    // ---- per-row merge of 4 sorted lists via packed u64 keys ----
    __syncthreads();
    u64* keys = (u64*)smem;                      // [row][85]: 4 lists x 21-stride
    {
        int row = wg * 32 + mf;
        int list = cs * 2 + h;
        u64* kp = keys + row * 85 + list * 21;
#pragma unroll
        for (int j = 0; j < 20; ++j) {
            unsigned u = __float_as_uint(val[j]);
            unsigned kk = (val[j] < 0.f) ? ~u : (u | 0x80000000u);
            kp[j] = ((u64)kk << 32) | (unsigned)(~ind[j]);
        }
    }
    __syncthreads();
    if (tid < 128) {
        const u64* kb = keys + tid * 85;
        int pp0 = 0, pp1 = 0, pp2 = 0, pp3 = 0;
        u64 h0v = kb[0], h1v = kb[21], h2v = kb[42], h3v = kb[63];
        int* op = idxo + ((size_t)b * N_ + n0 + tid) * K_;
        for (int k = 0; k < K_; ++k) {
            bool a = h0v >= h1v; u64 ma = a ? h0v : h1v; int sa = a ? 0 : 1;
            bool bb = h2v >= h3v; u64 mb = bb ? h2v : h3v; int sb = bb ? 2 : 3;
            bool c = ma >= mb; u64 mk = c ? ma : mb; int sl = c ? sa : sb;
            op[k] = (int)(~(unsigned)mk) & 0xFFF;
            if (sl == 0) { ++pp0; h0v = (pp0 < 20) ? kb[pp0] : 0ull; }
            else if (sl == 1) { ++pp1; h1v = (pp1 < 20) ? kb[21 + pp1] : 0ull; }
            else if (sl == 2) { ++pp2; h2v = (pp2 < 20) ? kb[42 + pp2] : 0ull; }
            else { ++pp3; h3v = (pp3 < 20) ? kb[63 + pp3] : 0ull; }
        }
    }
}

// ---------------- Kernel 3: qg[b][m][o2] ----------------
__global__ __launch_bounds__(256) void k_qg(const float* __restrict__ x,
                                            const float* __restrict__ W,
                                            float* __restrict__ qg) {
    __shared__ float Wl[64 * 129];
    __shared__ float xs[64 * 64];
    int b = blockIdx.x & 7, mt = blockIdx.x >> 3;
    int mbase = mt * 64;
    int tid = threadIdx.x;

    for (int i = 0; i < 32; ++i) {
        int lin = tid + 256 * i;
        int c = lin & 63, o2 = lin >> 6;
        float wv;
        if (o2 < 64) wv = W[o2 * 128 + c];
        else { int o = o2 - 64; wv = W[o * 128 + 64 + c] - W[o * 128 + c]; }
        Wl[c * 129 + o2] = wv;
    }
#pragma unroll
    for (int i = 0; i < 4; ++i) {
        int lin = tid + 256 * i;
        int c = lin >> 4, f = lin & 15;
        *(float4*)&xs[c * 64 + f * 4] =
            *(const float4*)&x[((size_t)b * C_ + c) * N_ + mbase + f * 4];
    }
    __syncthreads();

    int u = tid & 63, half = tid >> 6;
    float a0[16], a1[16];
#pragma unroll
    for (int j = 0; j < 16; ++j) { a0[j] = 0.f; a1[j] = 0.f; }
#pragma unroll 4
    for (int c = 0; c < 64; ++c) {
        float2 wv = *(const float2*)&Wl[c * 129 + 2 * u];
        const float4* xr = (const float4*)&xs[c * 64 + half * 16];
        float4 v0 = xr[0], v1 = xr[1], v2 = xr[2], v3 = xr[3];
        float xvv[16];
        xvv[0]=v0.x; xvv[1]=v0.y; xvv[2]=v0.z; xvv[3]=v0.w;
        xvv[4]=v1.x; xvv[5]=v1.y; xvv[6]=v1.z; xvv[7]=v1.w;
        xvv[8]=v2.x; xvv[9]=v2.y; xvv[10]=v2.z; xvv[11]=v2.w;
        xvv[12]=v3.x; xvv[13]=v3.y; xvv[14]=v3.z; xvv[15]=v3.w;
#pragma unroll
        for (int j = 0; j < 16; ++j) { a0[j] += wv.x * xvv[j]; a1[j] += wv.y * xvv[j]; }
    }
#pragma unroll
    for (int j = 0; j < 16; ++j) {
        int m = mbase + half * 16 + j;
        float2 o; o.x = a0[j]; o.y = a1[j];
        *(float2*)&qg[((size_t)b * N_ + m) * 128 + 2 * u] = o;
    }
}

// ---------------- Kernel 4: out = max_k leaky(q[ik][o] + g[n][o]) ----------------
// grid 1024 (8b x 128 nt of 32 rows) for gather-latency hiding
__global__ __launch_bounds__(256) void k_out(const float* __restrict__ qg,
                                             const int* __restrict__ idxi,
                                             float* __restrict__ out) {
    __shared__ float T[32][65];
    int b = blockIdx.x & 7, nt = blockIdx.x >> 3;
    int n0 = nt * 32;
    int tid = threadIdx.x;
    int w = tid >> 6, o = tid & 63;
    const float* qgb = qg + (size_t)b * N_ * 128;
    for (int i = 0; i < 8; ++i) {
        int nl = w * 8 + i;
        int n = n0 + nl;
        float gv = qgb[(size_t)n * 128 + 64 + o];
        const int* ip = idxi + ((size_t)b * N_ + n) * K_;
        float mx = -FLT_MAX;
#pragma unroll 5
        for (int k = 0; k < K_; ++k) {
            int ik = ip[k];
            float hh = qgb[(size_t)ik * 128 + o] + gv;
            hh = (hh >= 0.f) ? hh : 0.01f * hh;
            mx = fmaxf(mx, hh);
        }
        T[nl][o] = mx;
    }
    __syncthreads();
    int ow = tid >> 2, q = tid & 3;
#pragma unroll
    for (int j4 = 0; j4 < 2; ++j4) {
        int nl = q * 8 + j4 * 4;
        float4 v;
        v.x = T[nl + 0][ow]; v.y = T[nl + 1][ow];
        v.z = T[nl + 2][ow]; v.w = T[nl + 3][ow];
        *(float4*)&out[((size_t)b * 64 + ow) * N_ + n0 + nl] = v;
    }
}

extern "C" void kernel_launch(void* const* d_in, const int* in_sizes, int n_in,
                              void* d_out, int out_size, void* d_ws, size_t ws_size,
                              hipStream_t stream) {
    const float* x = (const float*)d_in[0];
    const float* W = (const float*)d_in[1];
    float* out = (float*)d_out;

    float*          xxh = (float*)d_ws;
    int*            idx = (int*)((char*)d_ws + OFF_IDX);
    float*          qg  = (float*)((char*)d_ws + OFF_QG);
    unsigned short* p0  = (unsigned short*)((char*)d_ws + OFF_P0);
    unsigned short* p1  = (unsigned short*)((char*)d_ws + OFF_P1);
    unsigned short* p2  = (unsigned short*)((char*)d_ws + OFF_P2);

    k_split<<<dim3(128), dim3(256), 0, stream>>>(x, p0, p1, p2, xxh);
    k_qg   <<<dim3(512), dim3(256), 0, stream>>>(x, W, qg);
    k_topk <<<dim3(256), dim3(512), 0, stream>>>(p0, p1, p2, xxh, idx);
    k_out  <<<dim3(1024), dim3(256), 0, stream>>>(qg, idx, out);
}

// Round 6
// 427.528 us; speedup vs baseline: 2.0013x; 1.0825x over previous
//
#include <hip/hip_runtime.h>
#include <cfloat>

#define B_ 8
#define C_ 64
#define N_ 4096
#define K_ 20
#define MARGIN 0.002f
#define CAP 28

typedef float f32x4v  __attribute__((ext_vector_type(4)));
typedef float f32x16v __attribute__((ext_vector_type(16)));
typedef _Float16 f16x8 __attribute__((ext_vector_type(8)));
typedef unsigned long long u64;

// ws layout (bytes):
//   xxn : B*N floats (= -xx/2, fp64-accumulated)  @ 0
//   idx : B*N*20 ints                             @ 131072
//   qg  : B*N*128 floats [b][m][o2]               @ 2752512
//   P0  : [b][seg=c/8][m][j=c%8] f16 limb0        @ 19529728 (4 MB)
//   P1  : limb1 (scale 2^-12)                     @ 23724032 (4 MB)
#define OFF_IDX 131072
#define OFF_QG  2752512
#define OFF_P0  19529728
#define OFF_P1  23724032

// ---------------- Kernel 1: 2-limb fp16 split + (-xx/2) ----------------
__global__ __launch_bounds__(256) void k_split(const float* __restrict__ x,
                                               unsigned short* __restrict__ p0,
                                               unsigned short* __restrict__ p1,
                                               float* __restrict__ xxn) {
    int b = blockIdx.x & 7, mt = blockIdx.x >> 3;
    int m = mt * 256 + threadIdx.x;
    const float* xb = x + (size_t)b * C_ * N_;
    double ss = 0.0;
#pragma unroll 1
    for (int seg = 0; seg < 8; ++seg) {
        unsigned short h0[8], h1[8];
#pragma unroll
        for (int j = 0; j < 8; ++j) {
            float v = xb[(size_t)(seg * 8 + j) * N_ + m];
            ss += (double)v * (double)v;
            _Float16 a = (_Float16)v;
            float r = v - (float)a;
            _Float16 bq = (_Float16)(r * 4096.f);
            h0[j] = __builtin_bit_cast(unsigned short, a);
            h1[j] = __builtin_bit_cast(unsigned short, bq);
        }
        uint4 q0, q1;
        q0.x = h0[0] | (h0[1] << 16); q0.y = h0[2] | (h0[3] << 16);
        q0.z = h0[4] | (h0[5] << 16); q0.w = h0[6] | (h0[7] << 16);
        q1.x = h1[0] | (h1[1] << 16); q1.y = h1[2] | (h1[3] << 16);
        q1.z = h1[4] | (h1[5] << 16); q1.w = h1[6] | (h1[7] << 16);
        size_t o16 = (size_t)(b * 8 + seg) * N_ + m;
        ((uint4*)p0)[o16] = q0;
        ((uint4*)p1)[o16] = q1;
    }
    xxn[b * N_ + m] = (float)(-0.5 * ss);
}

// score16: s = (A0+eps*A1)·(B0+eps*B1) + xxn  — full 2-limb product, 16 MFMA.
// Used IDENTICALLY by phase 1 and phase 2 (bit-identical recompute).
__device__ __forceinline__ void score16(const char* sm, const float* xxs,
                                        int mlb, int mf, int h,
                                        const f16x8 b0[4], const f16x8 b1[4],
                                        float s[16]) {
    const float c12 = 1.f / 4096.f;
    f32x16v acc1, acc2, acc3;
#pragma unroll
    for (int g2i = 0; g2i < 4; ++g2i) {
        f32x4v xv = *(const f32x4v*)&xxs[mlb + 4 * h + 8 * g2i];
#pragma unroll
        for (int q = 0; q < 4; ++q) {
            acc1[g2i * 4 + q] = xv[q];
            acc2[g2i * 4 + q] = 0.f;
            acc3[g2i * 4 + q] = 0.f;
        }
    }
#pragma unroll
    for (int kc = 0; kc < 4; ++kc) {
        int seg = kc * 2 + h;
        const char* pA = sm + seg * 4096 + (mlb + mf) * 16;
        f16x8 a0 = __builtin_bit_cast(f16x8, *(const f32x4v*)pA);
        f16x8 a1 = __builtin_bit_cast(f16x8, *(const f32x4v*)(pA + 32768));
        acc1 = __builtin_amdgcn_mfma_f32_32x32x16_f16(a0, b0[kc], acc1, 0, 0, 0);
        acc2 = __builtin_amdgcn_mfma_f32_32x32x16_f16(a0, b1[kc], acc2, 0, 0, 0);
        acc2 = __builtin_amdgcn_mfma_f32_32x32x16_f16(a1, b0[kc], acc2, 0, 0, 0);
        acc3 = __builtin_amdgcn_mfma_f32_32x32x16_f16(a1, b1[kc], acc3, 0, 0, 0);
    }
#pragma unroll
    for (int r = 0; r < 16; ++r)
        s[r] = acc1[r] + (acc2[r] + acc3[r] * c12) * c12;
}

// ---------------- Kernel 2: 3-phase kNN (2-limb-complete scores) ----------------
// grid 512 = 8b x 64nt (64 rows). block 512 = 8 waves: wg=w&1 rows, cs=w>>1
// candidate-quarter. LDS 81664 B -> 2 blocks/CU.
// map: staging 0..65536 (2 panels) | bufk 65536..79872 (64x28 u64) |
//      xxs 79872..80896 | cnt 80896 | T2 81152 | Trow 81408 | lists overlay 0..43264
__global__ __launch_bounds__(512, 4) void k_topk(const unsigned short* __restrict__ p0g,
                                                 const unsigned short* __restrict__ p1g,
                                                 const float* __restrict__ xxn,
                                                 int* __restrict__ idxo) {
    __shared__ __align__(16) char smem[81664];
    int b = blockIdx.x & 7, nt = blockIdx.x >> 3;
    int n0 = nt * 64;
    int tid = threadIdx.x;
    int w = tid >> 6, l = tid & 63, h = l >> 5, mf = l & 31;
    int cs = w >> 1, wg = w & 1;
    int rowl = wg * 32 + mf;
    int b8 = b * 8;
    const f32x4v* g0 = (const f32x4v*)p0g;
    const f32x4v* g1 = (const f32x4v*)p1g;
    u64*      bufk  = (u64*)(smem + 65536);
    float*    xxs   = (float*)(smem + 79872);
    int*      cntp  = (int*)(smem + 80896);
    float*    T2p   = (float*)(smem + 81152);
    unsigned* Trowp = (unsigned*)(smem + 81408);

    if (tid < 64) Trowp[tid] = 0x00800000u;     // mapped(-FLT_MAX)

    // B fragments (center rows), 2 limbs, register-resident
    f16x8 b0[4], b1[4];
#pragma unroll
    for (int kc = 0; kc < 4; ++kc) {
        int seg = kc * 2 + h;
        size_t gi = (size_t)(b8 + seg) * N_ + n0 + rowl;
        b0[kc] = __builtin_bit_cast(f16x8, g0[gi]);
        b1[kc] = __builtin_bit_cast(f16x8, g1[gi]);
    }

    float val[20];
#pragma unroll
    for (int j = 0; j < 20; ++j) val[j] = -FLT_MAX;
    float Tcur = -FLT_MAX;

    // ================= Phase 1: values-only pruned top-20 =================
#pragma unroll 1
    for (int ch = 0; ch < 16; ++ch) {
        __syncthreads();
#pragma unroll
        for (int i = 0; i < 8; ++i) {
            int lin = i * 512 + tid;            // 0..4095
            int panel = lin >> 11;
            int rem = lin & 2047;
            int seg = rem >> 8, ml = rem & 255;
            size_t gi = (size_t)(b8 + seg) * N_ + ch * 256 + ml;
            const f32x4v* src = panel ? g1 : g0;
            *(f32x4v*)(smem + panel * 32768 + seg * 4096 + ml * 16) = src[gi];
        }
        if (tid < 256) xxs[tid] = xxn[b * N_ + ch * 256 + tid];
        __syncthreads();
        {   // absorb other waves' thresholds
            unsigned tm = Trowp[rowl];
            float tf = (tm & 0x80000000u) ? __uint_as_float(tm & 0x7fffffffu)
                                          : __uint_as_float(~tm);
            Tcur = fmaxf(Tcur, tf);
        }
#pragma unroll
        for (int t = 0; t < 2; ++t) {
            int mlb = cs * 64 + t * 32;
            float s[16];
            score16(smem, xxs, mlb, mf, h, b0, b1, s);
            float m8[8];
#pragma unroll
            for (int r = 0; r < 8; ++r) m8[r] = fmaxf(s[r], s[r + 8]);
            float bmax = fmaxf(fmaxf(fmaxf(m8[0], m8[1]), fmaxf(m8[2], m8[3])),
                               fmaxf(fmaxf(m8[4], m8[5]), fmaxf(m8[6], m8[7])));
            while (__any(bmax > Tcur)) {
                if (bmax > Tcur) {
#pragma unroll
                    for (int j = 19; j >= 1; --j) {
                        bool c1 = bmax > val[j - 1];
                        float nv = c1 ? val[j - 1] : bmax;
                        val[j] = (bmax > val[j]) ? nv : val[j];
                    }
                    val[0] = fmaxf(val[0], bmax);
#pragma unroll
                    for (int r = 0; r < 16; ++r) s[r] = (s[r] == bmax) ? -FLT_MAX : s[r];
                }
                float v19 = val[19];
                Tcur = fmaxf(Tcur, fmaxf(v19, __shfl_xor(v19, 32)));
#pragma unroll
                for (int r = 0; r < 8; ++r) m8[r] = fmaxf(s[r], s[r + 8]);
                bmax = fmaxf(fmaxf(fmaxf(m8[0], m8[1]), fmaxf(m8[2], m8[3])),
                             fmaxf(fmaxf(m8[4], m8[5]), fmaxf(m8[6], m8[7])));
            }
        }
        {   // publish threshold
            unsigned mm = __float_as_uint(Tcur);
            unsigned mapped = (Tcur >= 0.f) ? (mm | 0x80000000u) : ~mm;
            atomicMax(Trowp + rowl, mapped);
        }
    }

    // ================= Merge: exact t* (20th-largest) per row =================
    __syncthreads();
    {
        float* lists = (float*)smem;             // [row][169]: 8 lists x 21-stride
        float* lp = lists + rowl * 169 + (cs * 2 + h) * 21;
#pragma unroll
        for (int j = 0; j < 20; ++j) lp[j] = val[j];
    }
    __syncthreads();
    if (tid < 64) {
        const float* lp = (const float*)smem + tid * 169;
        float hv[8]; int pp[8];
#pragma unroll
        for (int li = 0; li < 8; ++li) { hv[li] = lp[li * 21]; pp[li] = 0; }
        float tstar = -FLT_MAX;
        for (int k = 0; k < 20; ++k) {
            int i01 = (hv[0] >= hv[1]) ? 0 : 1; float m01 = fmaxf(hv[0], hv[1]);
            int i23 = (hv[2] >= hv[3]) ? 2 : 3; float m23 = fmaxf(hv[2], hv[3]);
            int i45 = (hv[4] >= hv[5]) ? 4 : 5; float m45 = fmaxf(hv[4], hv[5]);
            int i67 = (hv[6] >= hv[7]) ? 6 : 7; float m67 = fmaxf(hv[6], hv[7]);
            int i03 = (m01 >= m23) ? i01 : i23; float m03 = fmaxf(m01, m23);
            int i47 = (m45 >= m67) ? i45 : i67; float m47 = fmaxf(m45, m67);
            int ig = (m03 >= m47) ? i03 : i47;
            tstar = fmaxf(m03, m47);
#pragma unroll
            for (int li = 0; li < 8; ++li)
                if (li == ig) { ++pp[li]; hv[li] = (pp[li] < 20) ? lp[li * 21 + pp[li]] : -FLT_MAX; }
        }
        T2p[tid] = tstar - MARGIN;
        cntp[tid] = 0;
    }
    __syncthreads();
    float T2r = T2p[rowl];

    // ================= Phase 2: bit-identical re-scan + emit (score,idx) =================
#pragma unroll 1
    for (int ch = 0; ch < 16; ++ch) {
        __syncthreads();
#pragma unroll
        for (int i = 0; i < 8; ++i) {
            int lin = i * 512 + tid;
            int panel = lin >> 11;
            int rem = lin & 2047;
            int seg = rem >> 8, ml = rem & 255;
            size_t gi = (size_t)(b8 + seg) * N_ + ch * 256 + ml;
            const f32x4v* src = panel ? g1 : g0;
            *(f32x4v*)(smem + panel * 32768 + seg * 4096 + ml * 16) = src[gi];
        }
        if (tid < 256) xxs[tid] = xxn[b * N_ + ch * 256 + tid];
        __syncthreads();
#pragma unroll
        for (int t = 0; t < 2; ++t) {
            int mlb = cs * 64 + t * 32;
            float s[16];
            score16(smem, xxs, mlb, mf, h, b0, b1, s);
            unsigned msk = 0;
#pragma unroll
            for (int r = 0; r < 16; ++r) msk |= (s[r] >= T2r) ? (1u << r) : 0u;
            int cb = ch * 256 + mlb + 4 * h;
            while (msk) {
                int r = __ffs(msk) - 1;
                msk &= msk - 1;
                int cand = cb + (r & 3) + 8 * (r >> 2);
                float sv = s[r];
                unsigned sb = __float_as_uint(sv);
                unsigned kk = (sv < 0.f) ? ~sb : (sb | 0x80000000u);
                int slot = atomicAdd(cntp + rowl, 1);
                if (slot < CAP)
                    bufk[rowl * CAP + slot] = ((u64)kk << 32) | (unsigned)(~cand);
            }
        }
    }

    // ================= Phase 3: exact top-20 of survivors, write idx =================
    __syncthreads();
    if (tid < 64) {
        int c_ = cntp[tid]; c_ = (c_ > CAP) ? CAP : c_;
        u64* kp = bufk + tid * CAP;
        int* op = idxo + ((size_t)b * N_ + n0 + tid) * K_;
        for (int k = 0; k < K_; ++k) {
            u64 best = 0; int bs = 0;
            for (int s2 = 0; s2 < c_; ++s2) {
                bool g = kp[s2] > best;
                best = g ? kp[s2] : best;
                bs = g ? s2 : bs;
            }
            op[k] = (int)(~(unsigned)best) & 0xFFF;
            kp[bs] = 0;
        }
    }
}

// ---------------- Kernel 3: qg[b][m][o2] ----------------
__global__ __launch_bounds__(256) void k_qg(const float* __restrict__ x,
                                            const float* __restrict__ W,
                                            float* __restrict__ qg) {
    __shared__ float Wl[64 * 129];
    __shared__ float xs[64 * 64];
    int b = blockIdx.x & 7, mt = blockIdx.x >> 3;
    int mbase = mt * 64;
    int tid = threadIdx.x;

    for (int i = 0; i < 32; ++i) {
        int lin = tid + 256 * i;
        int c = lin & 63, o2 = lin >> 6;
        float wv;
        if (o2 < 64) wv = W[o2 * 128 + c];
        else { int o = o2 - 64; wv = W[o * 128 + 64 + c] - W[o * 128 + c]; }
        Wl[c * 129 + o2] = wv;
    }
#pragma unroll
    for (int i = 0; i < 4; ++i) {
        int lin = tid + 256 * i;
        int c = lin >> 4, f = lin & 15;
        *(float4*)&xs[c * 64 + f * 4] =
            *(const float4*)&x[((size_t)b * C_ + c) * N_ + mbase + f * 4];
    }
    __syncthreads();

    int u = tid & 63, half = tid >> 6;
    float a0[16], a1[16];
#pragma unroll
    for (int j = 0; j < 16; ++j) { a0[j] = 0.f; a1[j] = 0.f; }
#pragma unroll 4
    for (int c = 0; c < 64; ++c) {
        float2 wv = *(const float2*)&Wl[c * 129 + 2 * u];
        const float4* xr = (const float4*)&xs[c * 64 + half * 16];
        float4 v0 = xr[0], v1 = xr[1], v2 = xr[2], v3 = xr[3];
        float xvv[16];
        xvv[0]=v0.x; xvv[1]=v0.y; xvv[2]=v0.z; xvv[3]=v0.w;
        xvv[4]=v1.x; xvv[5]=v1.y; xvv[6]=v1.z; xvv[7]=v1.w;
        xvv[8]=v2.x; xvv[9]=v2.y; xvv[10]=v2.z; xvv[11]=v2.w;
        xvv[12]=v3.x; xvv[13]=v3.y; xvv[14]=v3.z; xvv[15]=v3.w;
#pragma unroll
        for (int j = 0; j < 16; ++j) { a0[j] += wv.x * xvv[j]; a1[j] += wv.y * xvv[j]; }
    }
#pragma unroll
    for (int j = 0; j < 16; ++j) {
        int m = mbase + half * 16 + j;
        float2 o; o.x = a0[j]; o.y = a1[j];
        *(float2*)&qg[((size_t)b * N_ + m) * 128 + 2 * u] = o;
    }
}

// ---------------- Kernel 4: out = max_k leaky(q[ik][o] + g[n][o]) ----------------
__global__ __launch_bounds__(256) void k_out(const float* __restrict__ qg,
                                             const int* __restrict__ idxi,
                                             float* __restrict__ out) {
    __shared__ float T[32][65];
    int b = blockIdx.x & 7, nt = blockIdx.x >> 3;
    int n0 = nt * 32;
    int tid = threadIdx.x;
    int w = tid >> 6, o = tid & 63;
    const float* qgb = qg + (size_t)b * N_ * 128;
    for (int i = 0; i < 8; ++i) {
        int nl = w * 8 + i;
        int n = n0 + nl;
        float gv = qgb[(size_t)n * 128 + 64 + o];
        const int* ip = idxi + ((size_t)b * N_ + n) * K_;
        float mx = -FLT_MAX;
#pragma unroll 5
        for (int k = 0; k < K_; ++k) {
            int ik = ip[k];
            float hh = qgb[(size_t)ik * 128 + o] + gv;
            hh = (hh >= 0.f) ? hh : 0.01f * hh;
            mx = fmaxf(mx, hh);
        }
        T[nl][o] = mx;
    }
    __syncthreads();
    int ow = tid >> 2, q = tid & 3;
#pragma unroll
    for (int j4 = 0; j4 < 2; ++j4) {
        int nl = q * 8 + j4 * 4;
        float4 v;
        v.x = T[nl + 0][ow]; v.y = T[nl + 1][ow];
        v.z = T[nl + 2][ow]; v.w = T[nl + 3][ow];
        *(float4*)&out[((size_t)b * 64 + ow) * N_ + n0 + nl] = v;
    }
}

extern "C" void kernel_launch(void* const* d_in, const int* in_sizes, int n_in,
                              void* d_out, int out_size, void* d_ws, size_t ws_size,
                              hipStream_t stream) {
    const float* x = (const float*)d_in[0];
    const float* W = (const float*)d_in[1];
    float* out = (float*)d_out;

    float*          xxn = (float*)d_ws;
    int*            idx = (int*)((char*)d_ws + OFF_IDX);
    float*          qg  = (float*)((char*)d_ws + OFF_QG);
    unsigned short* p0  = (unsigned short*)((char*)d_ws + OFF_P0);
    unsigned short* p1  = (unsigned short*)((char*)d_ws + OFF_P1);

    k_split<<<dim3(128), dim3(256), 0, stream>>>(x, p0, p1, xxn);
    k_qg   <<<dim3(512), dim3(256), 0, stream>>>(x, W, qg);
    k_topk <<<dim3(512), dim3(512), 0, stream>>>(p0, p1, xxn, idx);
    k_out  <<<dim3(1024), dim3(256), 0, stream>>>(qg, idx, out);
}

// Round 8
// 402.681 us; speedup vs baseline: 2.1248x; 1.0617x over previous
//
#include <hip/hip_runtime.h>
#include <cfloat>

#define B_ 8
#define C_ 64
#define N_ 4096
#define K_ 20
#define MARGIN 0.08f
#define CAP 48

typedef float f32x4v  __attribute__((ext_vector_type(4)));
typedef float f32x16v __attribute__((ext_vector_type(16)));
typedef _Float16 f16x8 __attribute__((ext_vector_type(8)));
typedef unsigned long long u64;

// ws layout (bytes):
//   xxn : B*N floats (= -xx/2, fp64-accumulated)  @ 0
//   idx : B*N*20 ints                             @ 131072
//   qg  : B*N*128 floats [b][m][o2]               @ 2752512  (16 MB)
//         -- ALSO used (before k_qg runs) as bufg: B*N*CAP u64 = 12.6 MB
//   P0  : [b][seg=c/8][m][j=c%8] f16 limb0        @ 19529728 (4 MB)
//   P1  : limb1 (scale 2^-12)                     @ 23724032 (4 MB)
#define OFF_IDX 131072
#define OFF_QG  2752512
#define OFF_P0  19529728
#define OFF_P1  23724032

// ---------------- Kernel 1: 2-limb fp16 split + (-xx/2) ----------------
__global__ __launch_bounds__(256) void k_split(const float* __restrict__ x,
                                               unsigned short* __restrict__ p0,
                                               unsigned short* __restrict__ p1,
                                               float* __restrict__ xxn) {
    int b = blockIdx.x & 7, mt = blockIdx.x >> 3;
    int m = mt * 256 + threadIdx.x;
    const float* xb = x + (size_t)b * C_ * N_;
    double ss = 0.0;
#pragma unroll 1
    for (int seg = 0; seg < 8; ++seg) {
        unsigned short h0[8], h1[8];
#pragma unroll
        for (int j = 0; j < 8; ++j) {
            float v = xb[(size_t)(seg * 8 + j) * N_ + m];
            ss += (double)v * (double)v;
            _Float16 a = (_Float16)v;
            float r = v - (float)a;
            _Float16 bq = (_Float16)(r * 4096.f);
            h0[j] = __builtin_bit_cast(unsigned short, a);
            h1[j] = __builtin_bit_cast(unsigned short, bq);
        }
        uint4 q0, q1;
        q0.x = h0[0] | (h0[1] << 16); q0.y = h0[2] | (h0[3] << 16);
        q0.z = h0[4] | (h0[5] << 16); q0.w = h0[6] | (h0[7] << 16);
        q1.x = h1[0] | (h1[1] << 16); q1.y = h1[2] | (h1[3] << 16);
        q1.z = h1[4] | (h1[5] << 16); q1.w = h1[6] | (h1[7] << 16);
        size_t o16 = (size_t)(b * 8 + seg) * N_ + m;
        ((uint4*)p0)[o16] = q0;
        ((uint4*)p1)[o16] = q1;
    }
    xxn[b * N_ + m] = (float)(-0.5 * ss);
}

// 1-limb approx score (phase 1): s = A0·B0 + xxn. 4 MFMA. Panel 0 only.
__device__ __forceinline__ void score4(const char* sm, const float* xxs,
                                       int mlb, int mf, int h,
                                       const f16x8 b0[4], float s[16]) {
    f32x16v acc;
#pragma unroll
    for (int g2i = 0; g2i < 4; ++g2i) {
        f32x4v xv = *(const f32x4v*)&xxs[mlb + 4 * h + 8 * g2i];
#pragma unroll
        for (int q = 0; q < 4; ++q) acc[g2i * 4 + q] = xv[q];
    }
#pragma unroll
    for (int kc = 0; kc < 4; ++kc) {
        int seg = kc * 2 + h;
        f16x8 a0 = __builtin_bit_cast(f16x8,
            *(const f32x4v*)(sm + seg * 4096 + (mlb + mf) * 16));
        acc = __builtin_amdgcn_mfma_f32_32x32x16_f16(a0, b0[kc], acc, 0, 0, 0);
    }
#pragma unroll
    for (int r = 0; r < 16; ++r) s[r] = acc[r];
}

// 2-limb precise score (phase 2, round-6-validated): 16 MFMA, panels 0+1.
__device__ __forceinline__ void score16(const char* sm, const float* xxs,
                                        int mlb, int mf, int h,
                                        const f16x8 b0[4], const f16x8 b1[4],
                                        float s[16]) {
    const float c12 = 1.f / 4096.f;
    f32x16v acc1, acc2, acc3;
#pragma unroll
    for (int g2i = 0; g2i < 4; ++g2i) {
        f32x4v xv = *(const f32x4v*)&xxs[mlb + 4 * h + 8 * g2i];
#pragma unroll
        for (int q = 0; q < 4; ++q) {
            acc1[g2i * 4 + q] = xv[q];
            acc2[g2i * 4 + q] = 0.f;
            acc3[g2i * 4 + q] = 0.f;
        }
    }
#pragma unroll
    for (int kc = 0; kc < 4; ++kc) {
        int seg = kc * 2 + h;
        const char* pA = sm + seg * 4096 + (mlb + mf) * 16;
        f16x8 a0 = __builtin_bit_cast(f16x8, *(const f32x4v*)pA);
        f16x8 a1 = __builtin_bit_cast(f16x8, *(const f32x4v*)(pA + 32768));
        acc1 = __builtin_amdgcn_mfma_f32_32x32x16_f16(a0, b0[kc], acc1, 0, 0, 0);
        acc2 = __builtin_amdgcn_mfma_f32_32x32x16_f16(a0, b1[kc], acc2, 0, 0, 0);
        acc2 = __builtin_amdgcn_mfma_f32_32x32x16_f16(a1, b0[kc], acc2, 0, 0, 0);
        acc3 = __builtin_amdgcn_mfma_f32_32x32x16_f16(a1, b1[kc], acc3, 0, 0, 0);
    }
#pragma unroll
    for (int r = 0; r < 16; ++r)
        s[r] = acc1[r] + (acc2[r] + acc3[r] * c12) * c12;
}

// ---------------- Kernel 2: 3-phase kNN ----------------
// grid 512 = 8b x 64nt (64 rows). block 512 = 8 waves: wg=w&1 rows, cs=w>>1.
// Phase 1: approx scan (deterministic, shfl-only pruning) -> t* -> T2.
// Phase 2: precise re-scan, emit (score,~idx) u64 keys to GLOBAL bufg.
// Phase 3: guarded load keys -> LDS, exact top-20 by key.
// LDS: panel0 0..32768 | panel1 32768..65536 | xxs 65536..66560 |
//      cnt 66560 | T2 66816 | lists overlay 0..43264 | keys overlay 0..24576
__global__ __launch_bounds__(512, 4) void k_topk(const unsigned short* __restrict__ p0g,
                                                 const unsigned short* __restrict__ p1g,
                                                 const float* __restrict__ xxn,
                                                 u64* __restrict__ bufg,
                                                 int* __restrict__ idxo) {
    __shared__ __align__(16) char smem[67072];
    int b = blockIdx.x & 7, nt = blockIdx.x >> 3;
    int n0 = nt * 64;
    int tid = threadIdx.x;
    int w = tid >> 6, l = tid & 63, h = l >> 5, mf = l & 31;
    int cs = w >> 1, wg = w & 1;
    int rowl = wg * 32 + mf;
    int b8 = b * 8;
    const f32x4v* g0 = (const f32x4v*)p0g;
    const f32x4v* g1 = (const f32x4v*)p1g;
    float* xxs  = (float*)(smem + 65536);
    int*   cntp = (int*)(smem + 66560);
    float* T2p  = (float*)(smem + 66816);

    // B fragments (center rows), 2 limbs, register-resident
    f16x8 b0[4], b1[4];
#pragma unroll
    for (int kc = 0; kc < 4; ++kc) {
        int seg = kc * 2 + h;
        size_t gi = (size_t)(b8 + seg) * N_ + n0 + rowl;
        b0[kc] = __builtin_bit_cast(f16x8, g0[gi]);
        b1[kc] = __builtin_bit_cast(f16x8, g1[gi]);
    }

    float val[20];
#pragma unroll
    for (int j = 0; j < 20; ++j) val[j] = -FLT_MAX;
    float Tcur = -FLT_MAX;

    // ================= Phase 1: approx scan (panel 0 only), pair-pruned =========
#pragma unroll 1
    for (int ch = 0; ch < 16; ++ch) {
        __syncthreads();
#pragma unroll
        for (int i = 0; i < 4; ++i) {
            int lin = i * 512 + tid;            // 0..2047
            int seg = lin >> 8, ml = lin & 255;
            *(f32x4v*)(smem + seg * 4096 + ml * 16) =
                g0[(size_t)(b8 + seg) * N_ + ch * 256 + ml];
        }
        if (tid < 256) xxs[tid] = xxn[b * N_ + ch * 256 + tid];
        __syncthreads();
#pragma unroll
        for (int t = 0; t < 2; ++t) {
            int mlb = cs * 64 + t * 32;
            float s[16];
            score4(smem, xxs, mlb, mf, h, b0, s);
            float m8[8];
#pragma unroll
            for (int r = 0; r < 8; ++r) m8[r] = fmaxf(s[r], s[r + 8]);
            float bmax = fmaxf(fmaxf(fmaxf(m8[0], m8[1]), fmaxf(m8[2], m8[3])),
                               fmaxf(fmaxf(m8[4], m8[5]), fmaxf(m8[6], m8[7])));
            while (__any(bmax > Tcur)) {
                if (bmax > Tcur) {
#pragma unroll
                    for (int j = 19; j >= 1; --j) {
                        bool c1 = bmax > val[j - 1];
                        float nv = c1 ? val[j - 1] : bmax;
                        val[j] = (bmax > val[j]) ? nv : val[j];
                    }
                    val[0] = fmaxf(val[0], bmax);
#pragma unroll
                    for (int r = 0; r < 16; ++r) s[r] = (s[r] == bmax) ? -FLT_MAX : s[r];
                }
                float v19 = val[19];
                Tcur = fmaxf(Tcur, fmaxf(v19, __shfl_xor(v19, 32)));
#pragma unroll
                for (int r = 0; r < 8; ++r) m8[r] = fmaxf(s[r], s[r + 8]);
                bmax = fmaxf(fmaxf(fmaxf(m8[0], m8[1]), fmaxf(m8[2], m8[3])),
                             fmaxf(fmaxf(m8[4], m8[5]), fmaxf(m8[6], m8[7])));
            }
        }
    }

    // ================= Merge: t* (approx 20th) per row =================
    __syncthreads();
    {
        float* lists = (float*)smem;             // [row][169]: 8 lists x 21-stride
        float* lp = lists + rowl * 169 + (cs * 2 + h) * 21;
#pragma unroll
        for (int j = 0; j < 20; ++j) lp[j] = val[j];
    }
    __syncthreads();
    if (tid < 64) {
        const float* lp = (const float*)smem + tid * 169;
        float hv[8]; int pp[8];
#pragma unroll
        for (int li = 0; li < 8; ++li) { hv[li] = lp[li * 21]; pp[li] = 0; }
        float tstar = -FLT_MAX;
        for (int k = 0; k < 20; ++k) {
            int i01 = (hv[0] >= hv[1]) ? 0 : 1; float m01 = fmaxf(hv[0], hv[1]);
            int i23 = (hv[2] >= hv[3]) ? 2 : 3; float m23 = fmaxf(hv[2], hv[3]);
            int i45 = (hv[4] >= hv[5]) ? 4 : 5; float m45 = fmaxf(hv[4], hv[5]);
            int i67 = (hv[6] >= hv[7]) ? 6 : 7; float m67 = fmaxf(hv[6], hv[7]);
            int i03 = (m01 >= m23) ? i01 : i23; float m03 = fmaxf(m01, m23);
            int i47 = (m45 >= m67) ? i45 : i67; float m47 = fmaxf(m45, m67);
            int ig = (m03 >= m47) ? i03 : i47;
            tstar = fmaxf(m03, m47);
#pragma unroll
            for (int li = 0; li < 8; ++li)
                if (li == ig) { ++pp[li]; hv[li] = (pp[li] < 20) ? lp[li * 21 + pp[li]] : -FLT_MAX; }
        }
        T2p[tid] = tstar - MARGIN;
        cntp[tid] = 0;
    }
    __syncthreads();
    float T2r = T2p[rowl];

    // ================= Phase 2: precise re-scan + emit keys to global =========
#pragma unroll 1
    for (int ch = 0; ch < 16; ++ch) {
        __syncthreads();
#pragma unroll
        for (int i = 0; i < 8; ++i) {
            int lin = i * 512 + tid;            // 0..4095
            int panel = lin >> 11;
            int rem = lin & 2047;
            int seg = rem >> 8, ml = rem & 255;
            size_t gi = (size_t)(b8 + seg) * N_ + ch * 256 + ml;
            const f32x4v* src = panel ? g1 : g0;
            *(f32x4v*)(smem + panel * 32768 + seg * 4096 + ml * 16) = src[gi];
        }
        if (tid < 256) xxs[tid] = xxn[b * N_ + ch * 256 + tid];
        __syncthreads();
#pragma unroll
        for (int t = 0; t < 2; ++t) {
            int mlb = cs * 64 + t * 32;
            float s[16];
            score16(smem, xxs, mlb, mf, h, b0, b1, s);
            unsigned msk = 0;
#pragma unroll
            for (int r = 0; r < 16; ++r) msk |= (s[r] >= T2r) ? (1u << r) : 0u;
            int cb = ch * 256 + mlb + 4 * h;
            while (msk) {
                int r = __ffs(msk) - 1;
                msk &= msk - 1;
                int cand = cb + (r & 3) + 8 * (r >> 2);
                float sv = s[r];
                unsigned sb = __float_as_uint(sv);
                unsigned kk = (sv < 0.f) ? ~sb : (sb | 0x80000000u);
                int slot = atomicAdd(cntp + rowl, 1);
                if (slot < CAP)
                    bufg[((size_t)(b * N_ + n0 + rowl)) * CAP + slot] =
                        ((u64)kk << 32) | (unsigned)(~cand);
            }
        }
    }

    // ================= Phase 3: load keys (guarded) + exact top-20 =============
    __syncthreads();
    u64* keys = (u64*)smem;                      // 64 x 48 u64 = 24576 B (staging dead)
#pragma unroll
    for (int i = 0; i < 6; ++i) {
        int p = i * 512 + tid;                   // 0..3071
        int row = p / CAP, slot = p % CAP;
        int c_ = cntp[row]; c_ = (c_ > CAP) ? CAP : c_;
        u64 key = 0;
        if (slot < c_)
            key = bufg[((size_t)(b * N_ + n0 + row)) * CAP + slot];
        keys[row * CAP + slot] = key;
    }
    __syncthreads();
    if (tid < 64) {
        int c_ = cntp[tid]; c_ = (c_ > CAP) ? CAP : c_;
        u64* kp = keys + tid * CAP;
        int* op = idxo + ((size_t)b * N_ + n0 + tid) * K_;
        for (int k = 0; k < K_; ++k) {
            u64 best = 0; int bs = 0;
            for (int s2 = 0; s2 < c_; ++s2) {
                bool g = kp[s2] > best;
                best = g ? kp[s2] : best;
                bs = g ? s2 : bs;
            }
            op[k] = (int)(~(unsigned)best) & 0xFFF;
            kp[bs] = 0;
        }
    }
}

// ---------------- Kernel 3: qg[b][m][o2]  (runs AFTER k_topk; overlays bufg) ---
__global__ __launch_bounds__(256) void k_qg(const float* __restrict__ x,
                                            const float* __restrict__ W,
                                            float* __restrict__ qg) {
    __shared__ float Wl[64 * 129];
    __shared__ float xs[64 * 64];
    int b = blockIdx.x & 7, mt = blockIdx.x >> 3;
    int mbase = mt * 64;
    int tid = threadIdx.x;

    for (int i = 0; i < 32; ++i) {
        int lin = tid + 256 * i;
        int c = lin & 63, o2 = lin >> 6;
        float wv;
        if (o2 < 64) wv = W[o2 * 128 + c];
        else { int o = o2 - 64; wv = W[o * 128 + 64 + c] - W[o * 128 + c]; }
        Wl[c * 129 + o2] = wv;
    }
#pragma unroll
    for (int i = 0; i < 4; ++i) {
        int lin = tid + 256 * i;
        int c = lin >> 4, f = lin & 15;
        *(float4*)&xs[c * 64 + f * 4] =
            *(const float4*)&x[((size_t)b * C_ + c) * N_ + mbase + f * 4];
    }
    __syncthreads();

    int u = tid & 63, half = tid >> 6;
    float a0[16], a1[16];
#pragma unroll
    for (int j = 0; j < 16; ++j) { a0[j] = 0.f; a1[j] = 0.f; }
#pragma unroll 4
    for (int c = 0; c < 64; ++c) {
        float2 wv = *(const float2*)&Wl[c * 129 + 2 * u];
        const float4* xr = (const float4*)&xs[c * 64 + half * 16];
        float4 v0 = xr[0], v1 = xr[1], v2 = xr[2], v3 = xr[3];
        float xvv[16];
        xvv[0]=v0.x; xvv[1]=v0.y; xvv[2]=v0.z; xvv[3]=v0.w;
        xvv[4]=v1.x; xvv[5]=v1.y; xvv[6]=v1.z; xvv[7]=v1.w;
        xvv[8]=v2.x; xvv[9]=v2.y; xvv[10]=v2.z; xvv[11]=v2.w;
        xvv[12]=v3.x; xvv[13]=v3.y; xvv[14]=v3.z; xvv[15]=v3.w;
#pragma unroll
        for (int j = 0; j < 16; ++j) { a0[j] += wv.x * xvv[j]; a1[j] += wv.y * xvv[j]; }
    }
#pragma unroll
    for (int j = 0; j < 16; ++j) {
        int m = mbase + half * 16 + j;
        float2 o; o.x = a0[j]; o.y = a1[j];
        *(float2*)&qg[((size_t)b * N_ + m) * 128 + 2 * u] = o;
    }
}

// ---------------- Kernel 4: out = max_k leaky(q[ik][o] + g[n][o]) ----------------
__global__ __launch_bounds__(256) void k_out(const float* __restrict__ qg,
                                             const int* __restrict__ idxi,
                                             float* __restrict__ out) {
    __shared__ float T[32][65];
    int b = blockIdx.x & 7, nt = blockIdx.x >> 3;
    int n0 = nt * 32;
    int tid = threadIdx.x;
    int w = tid >> 6, o = tid & 63;
    const float* qgb = qg + (size_t)b * N_ * 128;
    for (int i = 0; i < 8; ++i) {
        int nl = w * 8 + i;
        int n = n0 + nl;
        float gv = qgb[(size_t)n * 128 + 64 + o];
        const int* ip = idxi + ((size_t)b * N_ + n) * K_;
        float mx = -FLT_MAX;
#pragma unroll 5
        for (int k = 0; k < K_; ++k) {
            int ik = ip[k];
            float hh = qgb[(size_t)ik * 128 + o] + gv;
            hh = (hh >= 0.f) ? hh : 0.01f * hh;
            mx = fmaxf(mx, hh);
        }
        T[nl][o] = mx;
    }
    __syncthreads();
    int ow = tid >> 2, q = tid & 3;
#pragma unroll
    for (int j4 = 0; j4 < 2; ++j4) {
        int nl = q * 8 + j4 * 4;
        float4 v;
        v.x = T[nl + 0][ow]; v.y = T[nl + 1][ow];
        v.z = T[nl + 2][ow]; v.w = T[nl + 3][ow];
        *(float4*)&out[((size_t)b * 64 + ow) * N_ + n0 + nl] = v;
    }
}

extern "C" void kernel_launch(void* const* d_in, const int* in_sizes, int n_in,
                              void* d_out, int out_size, void* d_ws, size_t ws_size,
                              hipStream_t stream) {
    const float* x = (const float*)d_in[0];
    const float* W = (const float*)d_in[1];
    float* out = (float*)d_out;

    float*          xxn  = (float*)d_ws;
    int*            idx  = (int*)((char*)d_ws + OFF_IDX);
    float*          qg   = (float*)((char*)d_ws + OFF_QG);
    u64*            bufg = (u64*)((char*)d_ws + OFF_QG);   // overlays qg (topk before qg)
    unsigned short* p0   = (unsigned short*)((char*)d_ws + OFF_P0);
    unsigned short* p1   = (unsigned short*)((char*)d_ws + OFF_P1);

    k_split<<<dim3(128), dim3(256), 0, stream>>>(x, p0, p1, xxn);
    k_topk <<<dim3(512), dim3(512), 0, stream>>>(p0, p1, xxn, bufg, idx);
    k_qg   <<<dim3(512), dim3(256), 0, stream>>>(x, W, qg);
    k_out  <<<dim3(1024), dim3(256), 0, stream>>>(qg, idx, out);
}

// Round 9
// 400.960 us; speedup vs baseline: 2.1339x; 1.0043x over previous
//
#include <hip/hip_runtime.h>
#include <cfloat>

#define B_ 8
#define C_ 64
#define N_ 4096
#define K_ 20
#define MARGIN 0.08f
#define CAP 48

typedef float f32x4v  __attribute__((ext_vector_type(4)));
typedef float f32x16v __attribute__((ext_vector_type(16)));
typedef _Float16 f16x8 __attribute__((ext_vector_type(8)));
typedef unsigned long long u64;

// ws layout (bytes):
//   xxn : B*N floats (= -xx/2, fp64-accumulated)  @ 0
//   idx : B*N*20 ints                             @ 131072
//   qg  : B*N*128 floats [b][m][o2]               @ 2752512  (16 MB)
//         -- ALSO used (before k_qg runs) as bufg: B*N*CAP u64 = 12.6 MB
//   P0  : [b][seg=c/8][m][j=c%8] f16 limb0        @ 19529728 (4 MB)
//   P1  : limb1 (scale 2^-12)                     @ 23724032 (4 MB)
#define OFF_IDX 131072
#define OFF_QG  2752512
#define OFF_P0  19529728
#define OFF_P1  23724032

// ---------------- Kernel 1: 2-limb fp16 split + (-xx/2) ----------------
__global__ __launch_bounds__(256) void k_split(const float* __restrict__ x,
                                               unsigned short* __restrict__ p0,
                                               unsigned short* __restrict__ p1,
                                               float* __restrict__ xxn) {
    int b = blockIdx.x & 7, mt = blockIdx.x >> 3;
    int m = mt * 256 + threadIdx.x;
    const float* xb = x + (size_t)b * C_ * N_;
    double ss = 0.0;
#pragma unroll 1
    for (int seg = 0; seg < 8; ++seg) {
        unsigned short h0[8], h1[8];
#pragma unroll
        for (int j = 0; j < 8; ++j) {
            float v = xb[(size_t)(seg * 8 + j) * N_ + m];
            ss += (double)v * (double)v;
            _Float16 a = (_Float16)v;
            float r = v - (float)a;
            _Float16 bq = (_Float16)(r * 4096.f);
            h0[j] = __builtin_bit_cast(unsigned short, a);
            h1[j] = __builtin_bit_cast(unsigned short, bq);
        }
        uint4 q0, q1;
        q0.x = h0[0] | (h0[1] << 16); q0.y = h0[2] | (h0[3] << 16);
        q0.z = h0[4] | (h0[5] << 16); q0.w = h0[6] | (h0[7] << 16);
        q1.x = h1[0] | (h1[1] << 16); q1.y = h1[2] | (h1[3] << 16);
        q1.z = h1[4] | (h1[5] << 16); q1.w = h1[6] | (h1[7] << 16);
        size_t o16 = (size_t)(b * 8 + seg) * N_ + m;
        ((uint4*)p0)[o16] = q0;
        ((uint4*)p1)[o16] = q1;
    }
    xxn[b * N_ + m] = (float)(-0.5 * ss);
}

// 1-limb approx score (phase 1): s = A0·B0 + xxn. 4 MFMA. Panel 0 only.
__device__ __forceinline__ void score4(const char* sm, const float* xxs,
                                       int mlb, int mf, int h,
                                       const f16x8 b0[4], float s[16]) {
    f32x16v acc;
#pragma unroll
    for (int g2i = 0; g2i < 4; ++g2i) {
        f32x4v xv = *(const f32x4v*)&xxs[mlb + 4 * h + 8 * g2i];
#pragma unroll
        for (int q = 0; q < 4; ++q) acc[g2i * 4 + q] = xv[q];
    }
#pragma unroll
    for (int kc = 0; kc < 4; ++kc) {
        int seg = kc * 2 + h;
        f16x8 a0 = __builtin_bit_cast(f16x8,
            *(const f32x4v*)(sm + seg * 4096 + (mlb + mf) * 16));
        acc = __builtin_amdgcn_mfma_f32_32x32x16_f16(a0, b0[kc], acc, 0, 0, 0);
    }
#pragma unroll
    for (int r = 0; r < 16; ++r) s[r] = acc[r];
}

// 2-limb precise score (phase 2, validated r6/r8): 16 MFMA, panels 0+1.
__device__ __forceinline__ void score16(const char* sm, const float* xxs,
                                        int mlb, int mf, int h,
                                        const f16x8 b0[4], const f16x8 b1[4],
                                        float s[16]) {
    const float c12 = 1.f / 4096.f;
    f32x16v acc1, acc2, acc3;
#pragma unroll
    for (int g2i = 0; g2i < 4; ++g2i) {
        f32x4v xv = *(const f32x4v*)&xxs[mlb + 4 * h + 8 * g2i];
#pragma unroll
        for (int q = 0; q < 4; ++q) {
            acc1[g2i * 4 + q] = xv[q];
            acc2[g2i * 4 + q] = 0.f;
            acc3[g2i * 4 + q] = 0.f;
        }
    }
#pragma unroll
    for (int kc = 0; kc < 4; ++kc) {
        int seg = kc * 2 + h;
        const char* pA = sm + seg * 4096 + (mlb + mf) * 16;
        f16x8 a0 = __builtin_bit_cast(f16x8, *(const f32x4v*)pA);
        f16x8 a1 = __builtin_bit_cast(f16x8, *(const f32x4v*)(pA + 32768));
        acc1 = __builtin_amdgcn_mfma_f32_32x32x16_f16(a0, b0[kc], acc1, 0, 0, 0);
        acc2 = __builtin_amdgcn_mfma_f32_32x32x16_f16(a0, b1[kc], acc2, 0, 0, 0);
        acc2 = __builtin_amdgcn_mfma_f32_32x32x16_f16(a1, b0[kc], acc2, 0, 0, 0);
        acc3 = __builtin_amdgcn_mfma_f32_32x32x16_f16(a1, b1[kc], acc3, 0, 0, 0);
    }
#pragma unroll
    for (int r = 0; r < 16; ++r)
        s[r] = acc1[r] + (acc2[r] + acc3[r] * c12) * c12;
}

// ---------------- Kernel 2: 3-phase kNN ----------------
// grid 512 = 8b x 64nt (64 rows). block 512 = 8 waves: wg=w&1 rows, cs=w>>1.
// Phase 1: approx scan w/ row-wide shared pruning threshold (deterministic t* —
//          see proof in journal: Tcur <= t* at all times).
// Phase 2: precise re-scan, emit (score,~idx) u64 keys to GLOBAL bufg.
// Phase 3: guarded load keys -> LDS (stride CAP+1 vs bank conflicts), top-20.
// LDS: panel0 0..32768 | panel1 32768..65536 | xxs 65536..66560 |
//      cnt 66560 | T2 66816 | Trow 67072 | lists overlay 0..43264 |
//      keys overlay 0..25088 (64 x 49 u64)
__global__ __launch_bounds__(512, 4) void k_topk(const unsigned short* __restrict__ p0g,
                                                 const unsigned short* __restrict__ p1g,
                                                 const float* __restrict__ xxn,
                                                 u64* __restrict__ bufg,
                                                 int* __restrict__ idxo) {
    __shared__ __align__(16) char smem[67328];
    int b = blockIdx.x & 7, nt = blockIdx.x >> 3;
    int n0 = nt * 64;
    int tid = threadIdx.x;
    int w = tid >> 6, l = tid & 63, h = l >> 5, mf = l & 31;
    int cs = w >> 1, wg = w & 1;
    int rowl = wg * 32 + mf;
    int b8 = b * 8;
    const f32x4v* g0 = (const f32x4v*)p0g;
    const f32x4v* g1 = (const f32x4v*)p1g;
    float*    xxs   = (float*)(smem + 65536);
    int*      cntp  = (int*)(smem + 66560);
    float*    T2p   = (float*)(smem + 66816);
    unsigned* Trowp = (unsigned*)(smem + 67072);

    if (tid < 64) Trowp[tid] = 0x00800000u;     // mapped(-FLT_MAX)

    // B fragments (center rows), 2 limbs, register-resident
    f16x8 b0[4], b1[4];
#pragma unroll
    for (int kc = 0; kc < 4; ++kc) {
        int seg = kc * 2 + h;
        size_t gi = (size_t)(b8 + seg) * N_ + n0 + rowl;
        b0[kc] = __builtin_bit_cast(f16x8, g0[gi]);
        b1[kc] = __builtin_bit_cast(f16x8, g1[gi]);
    }

    float val[20];
#pragma unroll
    for (int j = 0; j < 20; ++j) val[j] = -FLT_MAX;
    float Tcur = -FLT_MAX;

    // ================= Phase 1: approx scan, row-shared pruning =================
#pragma unroll 1
    for (int ch = 0; ch < 16; ++ch) {
        __syncthreads();
#pragma unroll
        for (int i = 0; i < 4; ++i) {
            int lin = i * 512 + tid;            // 0..2047
            int seg = lin >> 8, ml = lin & 255;
            *(f32x4v*)(smem + seg * 4096 + ml * 16) =
                g0[(size_t)(b8 + seg) * N_ + ch * 256 + ml];
        }
        if (tid < 256) xxs[tid] = xxn[b * N_ + ch * 256 + tid];
        __syncthreads();
#pragma unroll
        for (int t = 0; t < 2; ++t) {
            int mlb = cs * 64 + t * 32;
            {   // absorb row-shared threshold
                unsigned tm = Trowp[rowl];
                float tf = (tm & 0x80000000u) ? __uint_as_float(tm & 0x7fffffffu)
                                              : __uint_as_float(~tm);
                Tcur = fmaxf(Tcur, tf);
            }
            float s[16];
            score4(smem, xxs, mlb, mf, h, b0, s);
            float m8[8];
#pragma unroll
            for (int r = 0; r < 8; ++r) m8[r] = fmaxf(s[r], s[r + 8]);
            float bmax = fmaxf(fmaxf(fmaxf(m8[0], m8[1]), fmaxf(m8[2], m8[3])),
                               fmaxf(fmaxf(m8[4], m8[5]), fmaxf(m8[6], m8[7])));
            while (__any(bmax > Tcur)) {
                if (bmax > Tcur) {
#pragma unroll
                    for (int j = 19; j >= 1; --j) {
                        bool c1 = bmax > val[j - 1];
                        float nv = c1 ? val[j - 1] : bmax;
                        val[j] = (bmax > val[j]) ? nv : val[j];
                    }
                    val[0] = fmaxf(val[0], bmax);
#pragma unroll
                    for (int r = 0; r < 16; ++r) s[r] = (s[r] == bmax) ? -FLT_MAX : s[r];
                }
                float v19 = val[19];
                Tcur = fmaxf(Tcur, fmaxf(v19, __shfl_xor(v19, 32)));
#pragma unroll
                for (int r = 0; r < 8; ++r) m8[r] = fmaxf(s[r], s[r + 8]);
                bmax = fmaxf(fmaxf(fmaxf(m8[0], m8[1]), fmaxf(m8[2], m8[3])),
                             fmaxf(fmaxf(m8[4], m8[5]), fmaxf(m8[6], m8[7])));
            }
            {   // publish own v19 (monotone atomicMax -> deterministic t*)
                unsigned mm = __float_as_uint(Tcur);
                unsigned mapped = (Tcur >= 0.f) ? (mm | 0x80000000u) : ~mm;
                atomicMax(Trowp + rowl, mapped);
            }
        }
    }

    // ================= Merge: t* (approx 20th) per row =================
    __syncthreads();
    {
        float* lists = (float*)smem;             // [row][169]: 8 lists x 21-stride
        float* lp = lists + rowl * 169 + (cs * 2 + h) * 21;
#pragma unroll
        for (int j = 0; j < 20; ++j) lp[j] = val[j];
    }
    __syncthreads();
    if (tid < 64) {
        const float* lp = (const float*)smem + tid * 169;
        float hv[8]; int pp[8];
#pragma unroll
        for (int li = 0; li < 8; ++li) { hv[li] = lp[li * 21]; pp[li] = 0; }
        float tstar = -FLT_MAX;
        for (int k = 0; k < 20; ++k) {
            int i01 = (hv[0] >= hv[1]) ? 0 : 1; float m01 = fmaxf(hv[0], hv[1]);
            int i23 = (hv[2] >= hv[3]) ? 2 : 3; float m23 = fmaxf(hv[2], hv[3]);
            int i45 = (hv[4] >= hv[5]) ? 4 : 5; float m45 = fmaxf(hv[4], hv[5]);
            int i67 = (hv[6] >= hv[7]) ? 6 : 7; float m67 = fmaxf(hv[6], hv[7]);
            int i03 = (m01 >= m23) ? i01 : i23; float m03 = fmaxf(m01, m23);
            int i47 = (m45 >= m67) ? i45 : i67; float m47 = fmaxf(m45, m67);
            int ig = (m03 >= m47) ? i03 : i47;
            tstar = fmaxf(m03, m47);
#pragma unroll
            for (int li = 0; li < 8; ++li)
                if (li == ig) { ++pp[li]; hv[li] = (pp[li] < 20) ? lp[li * 21 + pp[li]] : -FLT_MAX; }
        }
        T2p[tid] = tstar - MARGIN;
        cntp[tid] = 0;
    }
    __syncthreads();
    float T2r = T2p[rowl];

    // ================= Phase 2: precise re-scan + emit keys to global =========
#pragma unroll 1
    for (int ch = 0; ch < 16; ++ch) {
        __syncthreads();
#pragma unroll
        for (int i = 0; i < 8; ++i) {
            int lin = i * 512 + tid;            // 0..4095
            int panel = lin >> 11;
            int rem = lin & 2047;
            int seg = rem >> 8, ml = rem & 255;
            size_t gi = (size_t)(b8 + seg) * N_ + ch * 256 + ml;
            const f32x4v* src = panel ? g1 : g0;
            *(f32x4v*)(smem + panel * 32768 + seg * 4096 + ml * 16) = src[gi];
        }
        if (tid < 256) xxs[tid] = xxn[b * N_ + ch * 256 + tid];
        __syncthreads();
#pragma unroll
        for (int t = 0; t < 2; ++t) {
            int mlb = cs * 64 + t * 32;
            float s[16];
            score16(smem, xxs, mlb, mf, h, b0, b1, s);
            unsigned msk = 0;
#pragma unroll
            for (int r = 0; r < 16; ++r) msk |= (s[r] >= T2r) ? (1u << r) : 0u;
            int cb = ch * 256 + mlb + 4 * h;
            while (msk) {
                int r = __ffs(msk) - 1;
                msk &= msk - 1;
                int cand = cb + (r & 3) + 8 * (r >> 2);
                float sv = s[r];
                unsigned sb = __float_as_uint(sv);
                unsigned kk = (sv < 0.f) ? ~sb : (sb | 0x80000000u);
                int slot = atomicAdd(cntp + rowl, 1);
                if (slot < CAP)
                    bufg[((size_t)(b * N_ + n0 + rowl)) * CAP + slot] =
                        ((u64)kk << 32) | (unsigned)(~cand);
            }
        }
    }

    // ================= Phase 3: load keys (guarded) + exact top-20 =============
    __syncthreads();
    u64* keys = (u64*)smem;                      // 64 x 49 u64 (padded stride)
#pragma unroll
    for (int i = 0; i < 6; ++i) {
        int p = i * 512 + tid;                   // 0..3071
        int row = p / CAP, slot = p % CAP;
        int c_ = cntp[row]; c_ = (c_ > CAP) ? CAP : c_;
        u64 key = 0;
        if (slot < c_)
            key = bufg[((size_t)(b * N_ + n0 + row)) * CAP + slot];
        keys[row * (CAP + 1) + slot] = key;
    }
    __syncthreads();
    if (tid < 64) {
        int c_ = cntp[tid]; c_ = (c_ > CAP) ? CAP : c_;
        u64* kp = keys + tid * (CAP + 1);
        int* op = idxo + ((size_t)b * N_ + n0 + tid) * K_;
        for (int k = 0; k < K_; ++k) {
            u64 best = 0; int bs = 0;
            for (int s2 = 0; s2 < c_; ++s2) {
                bool g = kp[s2] > best;
                best = g ? kp[s2] : best;
                bs = g ? s2 : bs;
            }
            op[k] = (int)(~(unsigned)best) & 0xFFF;
            kp[bs] = 0;
        }
    }
}

// ---------------- Kernel 3: qg[b][m][o2]  (runs AFTER k_topk; overlays bufg) ---
__global__ __launch_bounds__(256) void k_qg(const float* __restrict__ x,
                                            const float* __restrict__ W,
                                            float* __restrict__ qg) {
    __shared__ float Wl[64 * 129];
    __shared__ float xs[64 * 64];
    int b = blockIdx.x & 7, mt = blockIdx.x >> 3;
    int mbase = mt * 64;
    int tid = threadIdx.x;

    for (int i = 0; i < 32; ++i) {
        int lin = tid + 256 * i;
        int c = lin & 63, o2 = lin >> 6;
        float wv;
        if (o2 < 64) wv = W[o2 * 128 + c];
        else { int o = o2 - 64; wv = W[o * 128 + 64 + c] - W[o * 128 + c]; }
        Wl[c * 129 + o2] = wv;
    }
#pragma unroll
    for (int i = 0; i < 4; ++i) {
        int lin = tid + 256 * i;
        int c = lin >> 4, f = lin & 15;
        *(float4*)&xs[c * 64 + f * 4] =
            *(const float4*)&x[((size_t)b * C_ + c) * N_ + mbase + f * 4];
    }
    __syncthreads();

    int u = tid & 63, half = tid >> 6;
    float a0[16], a1[16];
#pragma unroll
    for (int j = 0; j < 16; ++j) { a0[j] = 0.f; a1[j] = 0.f; }
#pragma unroll 4
    for (int c = 0; c < 64; ++c) {
        float2 wv = *(const float2*)&Wl[c * 129 + 2 * u];
        const float4* xr = (const float4*)&xs[c * 64 + half * 16];
        float4 v0 = xr[0], v1 = xr[1], v2 = xr[2], v3 = xr[3];
        float xvv[16];
        xvv[0]=v0.x; xvv[1]=v0.y; xvv[2]=v0.z; xvv[3]=v0.w;
        xvv[4]=v1.x; xvv[5]=v1.y; xvv[6]=v1.z; xvv[7]=v1.w;
        xvv[8]=v2.x; xvv[9]=v2.y; xvv[10]=v2.z; xvv[11]=v2.w;
        xvv[12]=v3.x; xvv[13]=v3.y; xvv[14]=v3.z; xvv[15]=v3.w;
#pragma unroll
        for (int j = 0; j < 16; ++j) { a0[j] += wv.x * xvv[j]; a1[j] += wv.y * xvv[j]; }
    }
#pragma unroll
    for (int j = 0; j < 16; ++j) {
        int m = mbase + half * 16 + j;
        float2 o; o.x = a0[j]; o.y = a1[j];
        *(float2*)&qg[((size_t)b * N_ + m) * 128 + 2 * u] = o;
    }
}

// ---------------- Kernel 4: out = max_k leaky(q[ik][o] + g[n][o]) ----------------
__global__ __launch_bounds__(256) void k_out(const float* __restrict__ qg,
                                             const int* __restrict__ idxi,
                                             float* __restrict__ out) {
    __shared__ float T[32][65];
    int b = blockIdx.x & 7, nt = blockIdx.x >> 3;
    int n0 = nt * 32;
    int tid = threadIdx.x;
    int w = tid >> 6, o = tid & 63;
    const float* qgb = qg + (size_t)b * N_ * 128;
    for (int i = 0; i < 8; ++i) {
        int nl = w * 8 + i;
        int n = n0 + nl;
        float gv = qgb[(size_t)n * 128 + 64 + o];
        const int* ip = idxi + ((size_t)b * N_ + n) * K_;
        float mx = -FLT_MAX;
#pragma unroll 5
        for (int k = 0; k < K_; ++k) {
            int ik = ip[k];
            float hh = qgb[(size_t)ik * 128 + o] + gv;
            hh = (hh >= 0.f) ? hh : 0.01f * hh;
            mx = fmaxf(mx, hh);
        }
        T[nl][o] = mx;
    }
    __syncthreads();
    int ow = tid >> 2, q = tid & 3;
#pragma unroll
    for (int j4 = 0; j4 < 2; ++j4) {
        int nl = q * 8 + j4 * 4;
        float4 v;
        v.x = T[nl + 0][ow]; v.y = T[nl + 1][ow];
        v.z = T[nl + 2][ow]; v.w = T[nl + 3][ow];
        *(float4*)&out[((size_t)b * 64 + ow) * N_ + n0 + nl] = v;
    }
}

extern "C" void kernel_launch(void* const* d_in, const int* in_sizes, int n_in,
                              void* d_out, int out_size, void* d_ws, size_t ws_size,
                              hipStream_t stream) {
    const float* x = (const float*)d_in[0];
    const float* W = (const float*)d_in[1];
    float* out = (float*)d_out;

    float*          xxn  = (float*)d_ws;
    int*            idx  = (int*)((char*)d_ws + OFF_IDX);
    float*          qg   = (float*)((char*)d_ws + OFF_QG);
    u64*            bufg = (u64*)((char*)d_ws + OFF_QG);   // overlays qg (topk before qg)
    unsigned short* p0   = (unsigned short*)((char*)d_ws + OFF_P0);
    unsigned short* p1   = (unsigned short*)((char*)d_ws + OFF_P1);

    k_split<<<dim3(128), dim3(256), 0, stream>>>(x, p0, p1, xxn);
    k_topk <<<dim3(512), dim3(512), 0, stream>>>(p0, p1, xxn, bufg, idx);
    k_qg   <<<dim3(512), dim3(256), 0, stream>>>(x, W, qg);
    k_out  <<<dim3(1024), dim3(256), 0, stream>>>(qg, idx, out);
}

// Round 10
// 254.479 us; speedup vs baseline: 3.3622x; 1.5756x over previous
//
#include <hip/hip_runtime.h>
#include <cfloat>

#define B_ 8
#define C_ 64
#define N_ 4096
#define K_ 20
#define MARGIN 0.08f
#define CAP 64

typedef float f32x4v  __attribute__((ext_vector_type(4)));
typedef float f32x16v __attribute__((ext_vector_type(16)));
typedef _Float16 f16x8 __attribute__((ext_vector_type(8)));
typedef unsigned long long u64;

// ws layout (bytes):
//   xxn : B*N floats (= -xx/2, fp64-accumulated)  @ 0
//   idx : B*N*20 ints                             @ 131072
//   qg  : B*N*128 floats [b][m][o2]               @ 2752512  (16 MB)
//         -- ALSO used (before k_qg runs) as bufg: B*N*CAP u64 = 16 MB exact
//   P0  : [b][seg=c/8][m][j=c%8] f16 limb0        @ 19529728 (4 MB)
//   P1  : limb1 (scale 2^-12)                     @ 23724032 (4 MB)
#define OFF_IDX 131072
#define OFF_QG  2752512
#define OFF_P0  19529728
#define OFF_P1  23724032

// ---------------- Kernel 1: 2-limb fp16 split + (-xx/2) ----------------
__global__ __launch_bounds__(256) void k_split(const float* __restrict__ x,
                                               unsigned short* __restrict__ p0,
                                               unsigned short* __restrict__ p1,
                                               float* __restrict__ xxn) {
    int b = blockIdx.x & 7, mt = blockIdx.x >> 3;
    int m = mt * 256 + threadIdx.x;
    const float* xb = x + (size_t)b * C_ * N_;
    double ss = 0.0;
#pragma unroll 1
    for (int seg = 0; seg < 8; ++seg) {
        unsigned short h0[8], h1[8];
#pragma unroll
        for (int j = 0; j < 8; ++j) {
            float v = xb[(size_t)(seg * 8 + j) * N_ + m];
            ss += (double)v * (double)v;
            _Float16 a = (_Float16)v;
            float r = v - (float)a;
            _Float16 bq = (_Float16)(r * 4096.f);
            h0[j] = __builtin_bit_cast(unsigned short, a);
            h1[j] = __builtin_bit_cast(unsigned short, bq);
        }
        uint4 q0, q1;
        q0.x = h0[0] | (h0[1] << 16); q0.y = h0[2] | (h0[3] << 16);
        q0.z = h0[4] | (h0[5] << 16); q0.w = h0[6] | (h0[7] << 16);
        q1.x = h1[0] | (h1[1] << 16); q1.y = h1[2] | (h1[3] << 16);
        q1.z = h1[4] | (h1[5] << 16); q1.w = h1[6] | (h1[7] << 16);
        size_t o16 = (size_t)(b * 8 + seg) * N_ + m;
        ((uint4*)p0)[o16] = q0;
        ((uint4*)p1)[o16] = q1;
    }
    xxn[b * N_ + m] = (float)(-0.5 * ss);
}

// 1-limb approx score (phase 1): s = A0·B0 + xxn. 4 MFMA. Panel 0 only.
__device__ __forceinline__ void score4(const char* sm, const float* xxs,
                                       int mlb, int mf, int h,
                                       const f16x8 b0[4], float s[16]) {
    f32x16v acc;
#pragma unroll
    for (int g2i = 0; g2i < 4; ++g2i) {
        f32x4v xv = *(const f32x4v*)&xxs[mlb + 4 * h + 8 * g2i];
#pragma unroll
        for (int q = 0; q < 4; ++q) acc[g2i * 4 + q] = xv[q];
    }
#pragma unroll
    for (int kc = 0; kc < 4; ++kc) {
        int seg = kc * 2 + h;
        f16x8 a0 = __builtin_bit_cast(f16x8,
            *(const f32x4v*)(sm + seg * 4096 + (mlb + mf) * 16));
        acc = __builtin_amdgcn_mfma_f32_32x32x16_f16(a0, b0[kc], acc, 0, 0, 0);
    }
#pragma unroll
    for (int r = 0; r < 16; ++r) s[r] = acc[r];
}

// 2-limb precise score (phase 2, validated r6/r8/r9): 16 MFMA, panels 0+1.
__device__ __forceinline__ void score16(const char* sm, const float* xxs,
                                        int mlb, int mf, int h,
                                        const f16x8 b0[4], const f16x8 b1[4],
                                        float s[16]) {
    const float c12 = 1.f / 4096.f;
    f32x16v acc1, acc2, acc3;
#pragma unroll
    for (int g2i = 0; g2i < 4; ++g2i) {
        f32x4v xv = *(const f32x4v*)&xxs[mlb + 4 * h + 8 * g2i];
#pragma unroll
        for (int q = 0; q < 4; ++q) {
            acc1[g2i * 4 + q] = xv[q];
            acc2[g2i * 4 + q] = 0.f;
            acc3[g2i * 4 + q] = 0.f;
        }
    }
#pragma unroll
    for (int kc = 0; kc < 4; ++kc) {
        int seg = kc * 2 + h;
        const char* pA = sm + seg * 4096 + (mlb + mf) * 16;
        f16x8 a0 = __builtin_bit_cast(f16x8, *(const f32x4v*)pA);
        f16x8 a1 = __builtin_bit_cast(f16x8, *(const f32x4v*)(pA + 32768));
        acc1 = __builtin_amdgcn_mfma_f32_32x32x16_f16(a0, b0[kc], acc1, 0, 0, 0);
        acc2 = __builtin_amdgcn_mfma_f32_32x32x16_f16(a0, b1[kc], acc2, 0, 0, 0);
        acc2 = __builtin_amdgcn_mfma_f32_32x32x16_f16(a1, b0[kc], acc2, 0, 0, 0);
        acc3 = __builtin_amdgcn_mfma_f32_32x32x16_f16(a1, b1[kc], acc3, 0, 0, 0);
    }
#pragma unroll
    for (int r = 0; r < 16; ++r)
        s[r] = acc1[r] + (acc2[r] + acc3[r] * c12) * c12;
}

// ---------------- Kernel 2: kNN via block-maxima threshold ----------------
// grid 512 = 8b x 64nt (64 rows). block 512 = 8 waves: wg=w&1 rows, cs=w>>1.
// Phase 1: approx scan; per t-iter write per-row 32-cand max to M[64][129]
//          (128 maxima/row). NO inserts, NO atomics.
// Select:  t* = 20th of per-row maxima (4 lanes/row, pooled top-8 lists --
//          truncation is one-sided-safe: only lowers t*). T2 = t* - MARGIN.
//          Validity: 20th-of-block-maxima <= 20th-of-all-scores.
// Phase 2: precise re-scan, emit (score,~idx) u64 keys >= T2 to GLOBAL bufg.
// Phase 3: guarded load keys -> LDS, exact top-20 by key (r8/r9-validated).
// LDS: pan0 0..32768 | pan1/M 32768..65792 | xxs 65792..66816 |
//      cnt 66816..67072 | T2 67072..67328 | L overlay 0..8448 | keys 0..33280
__global__ __launch_bounds__(512, 4) void k_topk(const unsigned short* __restrict__ p0g,
                                                 const unsigned short* __restrict__ p1g,
                                                 const float* __restrict__ xxn,
                                                 u64* __restrict__ bufg,
                                                 int* __restrict__ idxo) {
    __shared__ __align__(16) char smem[67328];
    int b = blockIdx.x & 7, nt = blockIdx.x >> 3;
    int n0 = nt * 64;
    int tid = threadIdx.x;
    int w = tid >> 6, l = tid & 63, h = l >> 5, mf = l & 31;
    int cs = w >> 1, wg = w & 1;
    int rowl = wg * 32 + mf;
    int b8 = b * 8;
    const f32x4v* g0 = (const f32x4v*)p0g;
    const f32x4v* g1 = (const f32x4v*)p1g;
    float* Mp   = (float*)(smem + 32768);        // [64][129]
    float* xxs  = (float*)(smem + 65792);
    int*   cntp = (int*)(smem + 66816);
    float* T2p  = (float*)(smem + 67072);

    // B fragments (center rows), 2 limbs, register-resident
    f16x8 b0[4], b1[4];
#pragma unroll
    for (int kc = 0; kc < 4; ++kc) {
        int seg = kc * 2 + h;
        size_t gi = (size_t)(b8 + seg) * N_ + n0 + rowl;
        b0[kc] = __builtin_bit_cast(f16x8, g0[gi]);
        b1[kc] = __builtin_bit_cast(f16x8, g1[gi]);
    }

    // ================= Phase 1: approx scan -> per-row block maxima ===========
#pragma unroll 1
    for (int ch = 0; ch < 16; ++ch) {
        __syncthreads();
#pragma unroll
        for (int i = 0; i < 4; ++i) {
            int lin = i * 512 + tid;            // 0..2047
            int seg = lin >> 8, ml = lin & 255;
            *(f32x4v*)(smem + seg * 4096 + ml * 16) =
                g0[(size_t)(b8 + seg) * N_ + ch * 256 + ml];
        }
        if (tid < 256) xxs[tid] = xxn[b * N_ + ch * 256 + tid];
        __syncthreads();
#pragma unroll
        for (int t = 0; t < 2; ++t) {
            int mlb = cs * 64 + t * 32;
            float s[16];
            score4(smem, xxs, mlb, mf, h, b0, s);
            float m8[8];
#pragma unroll
            for (int r = 0; r < 8; ++r) m8[r] = fmaxf(s[r], s[r + 8]);
            float mx = fmaxf(fmaxf(fmaxf(m8[0], m8[1]), fmaxf(m8[2], m8[3])),
                             fmaxf(fmaxf(m8[4], m8[5]), fmaxf(m8[6], m8[7])));
            mx = fmaxf(mx, __shfl_xor(mx, 32));
            if (l < 32)
                Mp[rowl * 129 + ch * 8 + t * 4 + cs] = mx;
        }
    }

    // ================= Select: t* = 20th of 128 maxima per row ================
    __syncthreads();
    if (tid < 256) {                             // 4 lanes per row, top-8 each
        int row = tid >> 2, q = tid & 3;
        const float* mrow = Mp + row * 129 + q * 32;
        float v8[8];
#pragma unroll
        for (int j = 0; j < 8; ++j) v8[j] = -FLT_MAX;
#pragma unroll
        for (int i = 0; i < 32; ++i) {
            float v = mrow[i];
#pragma unroll
            for (int j = 7; j >= 1; --j) {
                bool c1 = v > v8[j - 1];
                float nv = c1 ? v8[j - 1] : v;
                v8[j] = (v > v8[j]) ? nv : v8[j];
            }
            v8[0] = fmaxf(v8[0], v);
        }
        float* lp = (float*)smem + row * 33 + q * 8;  // L overlay on pan0 (dead)
#pragma unroll
        for (int j = 0; j < 8; ++j) lp[j] = v8[j];
    }
    __syncthreads();
    if (tid < 64) {                              // 4-way merge to the 20th
        const float* lp = (const float*)smem + tid * 33;
        float hv0 = lp[0], hv1 = lp[8], hv2 = lp[16], hv3 = lp[24];
        int p0 = 0, p1 = 0, p2 = 0, p3 = 0;
        float tstar = -FLT_MAX;
        for (int k = 0; k < 20; ++k) {
            bool a = hv0 >= hv1; float ma = a ? hv0 : hv1; int sa = a ? 0 : 1;
            bool bb = hv2 >= hv3; float mb = bb ? hv2 : hv3; int sb = bb ? 2 : 3;
            bool c = ma >= mb; tstar = c ? ma : mb; int sl = c ? sa : sb;
            if (sl == 0) { ++p0; hv0 = (p0 < 8) ? lp[p0] : -FLT_MAX; }
            else if (sl == 1) { ++p1; hv1 = (p1 < 8) ? lp[8 + p1] : -FLT_MAX; }
            else if (sl == 2) { ++p2; hv2 = (p2 < 8) ? lp[16 + p2] : -FLT_MAX; }
            else { ++p3; hv3 = (p3 < 8) ? lp[24 + p3] : -FLT_MAX; }
        }
        T2p[tid] = tstar - MARGIN;
        cntp[tid] = 0;
    }
    __syncthreads();
    float T2r = T2p[rowl];

    // ================= Phase 2: precise re-scan + emit keys to global =========
#pragma unroll 1
    for (int ch = 0; ch < 16; ++ch) {
        __syncthreads();
#pragma unroll
        for (int i = 0; i < 8; ++i) {
            int lin = i * 512 + tid;            // 0..4095
            int panel = lin >> 11;
            int rem = lin & 2047;
            int seg = rem >> 8, ml = rem & 255;
            size_t gi = (size_t)(b8 + seg) * N_ + ch * 256 + ml;
            const f32x4v* src = panel ? g1 : g0;
            *(f32x4v*)(smem + panel * 32768 + seg * 4096 + ml * 16) = src[gi];
        }
        if (tid < 256) xxs[tid] = xxn[b * N_ + ch * 256 + tid];
        __syncthreads();
#pragma unroll
        for (int t = 0; t < 2; ++t) {
            int mlb = cs * 64 + t * 32;
            float s[16];
            score16(smem, xxs, mlb, mf, h, b0, b1, s);
            unsigned msk = 0;
#pragma unroll
            for (int r = 0; r < 16; ++r) msk |= (s[r] >= T2r) ? (1u << r) : 0u;
            int cb = ch * 256 + mlb + 4 * h;
            while (msk) {
                int r = __ffs(msk) - 1;
                msk &= msk - 1;
                int cand = cb + (r & 3) + 8 * (r >> 2);
                float sv = s[r];
                unsigned sb = __float_as_uint(sv);
                unsigned kk = (sv < 0.f) ? ~sb : (sb | 0x80000000u);
                int slot = atomicAdd(cntp + rowl, 1);
                if (slot < CAP)
                    bufg[((size_t)(b * N_ + n0 + rowl)) * CAP + slot] =
                        ((u64)kk << 32) | (unsigned)(~cand);
            }
        }
    }

    // ================= Phase 3: load keys (guarded) + exact top-20 =============
    __syncthreads();
    u64* keys = (u64*)smem;                      // 64 x 65 u64 (padded stride)
#pragma unroll
    for (int i = 0; i < 8; ++i) {
        int p = i * 512 + tid;                   // 0..4095
        int row = p >> 6, slot = p & 63;
        int c_ = cntp[row]; c_ = (c_ > CAP) ? CAP : c_;
        u64 key = 0;
        if (slot < c_)
            key = bufg[((size_t)(b * N_ + n0 + row)) * CAP + slot];
        keys[row * (CAP + 1) + slot] = key;
    }
    __syncthreads();
    if (tid < 64) {
        int c_ = cntp[tid]; c_ = (c_ > CAP) ? CAP : c_;
        u64* kp = keys + tid * (CAP + 1);
        int* op = idxo + ((size_t)b * N_ + n0 + tid) * K_;
        for (int k = 0; k < K_; ++k) {
            u64 best = 0; int bs = 0;
            for (int s2 = 0; s2 < c_; ++s2) {
                bool g = kp[s2] > best;
                best = g ? kp[s2] : best;
                bs = g ? s2 : bs;
            }
            op[k] = (int)(~(unsigned)best) & 0xFFF;
            kp[bs] = 0;
        }
    }
}

// ---------------- Kernel 3: qg[b][m][o2]  (runs AFTER k_topk; overlays bufg) ---
__global__ __launch_bounds__(256) void k_qg(const float* __restrict__ x,
                                            const float* __restrict__ W,
                                            float* __restrict__ qg) {
    __shared__ float Wl[64 * 129];
    __shared__ float xs[64 * 64];
    int b = blockIdx.x & 7, mt = blockIdx.x >> 3;
    int mbase = mt * 64;
    int tid = threadIdx.x;

    for (int i = 0; i < 32; ++i) {
        int lin = tid + 256 * i;
        int c = lin & 63, o2 = lin >> 6;
        float wv;
        if (o2 < 64) wv = W[o2 * 128 + c];
        else { int o = o2 - 64; wv = W[o * 128 + 64 + c] - W[o * 128 + c]; }
        Wl[c * 129 + o2] = wv;
    }
#pragma unroll
    for (int i = 0; i < 4; ++i) {
        int lin = tid + 256 * i;
        int c = lin >> 4, f = lin & 15;
        *(float4*)&xs[c * 64 + f * 4] =
            *(const float4*)&x[((size_t)b * C_ + c) * N_ + mbase + f * 4];
    }
    __syncthreads();

    int u = tid & 63, half = tid >> 6;
    float a0[16], a1[16];
#pragma unroll
    for (int j = 0; j < 16; ++j) { a0[j] = 0.f; a1[j] = 0.f; }
#pragma unroll 4
    for (int c = 0; c < 64; ++c) {
        float2 wv = *(const float2*)&Wl[c * 129 + 2 * u];
        const float4* xr = (const float4*)&xs[c * 64 + half * 16];
        float4 v0 = xr[0], v1 = xr[1], v2 = xr[2], v3 = xr[3];
        float xvv[16];
        xvv[0]=v0.x; xvv[1]=v0.y; xvv[2]=v0.z; xvv[3]=v0.w;
        xvv[4]=v1.x; xvv[5]=v1.y; xvv[6]=v1.z; xvv[7]=v1.w;
        xvv[8]=v2.x; xvv[9]=v2.y; xvv[10]=v2.z; xvv[11]=v2.w;
        xvv[12]=v3.x; xvv[13]=v3.y; xvv[14]=v3.z; xvv[15]=v3.w;
#pragma unroll
        for (int j = 0; j < 16; ++j) { a0[j] += wv.x * xvv[j]; a1[j] += wv.y * xvv[j]; }
    }
#pragma unroll
    for (int j = 0; j < 16; ++j) {
        int m = mbase + half * 16 + j;
        float2 o; o.x = a0[j]; o.y = a1[j];
        *(float2*)&qg[((size_t)b * N_ + m) * 128 + 2 * u] = o;
    }
}

// ---------------- Kernel 4: out = max_k leaky(q[ik][o] + g[n][o]) ----------------
__global__ __launch_bounds__(256) void k_out(const float* __restrict__ qg,
                                             const int* __restrict__ idxi,
                                             float* __restrict__ out) {
    __shared__ float T[32][65];
    int b = blockIdx.x & 7, nt = blockIdx.x >> 3;
    int n0 = nt * 32;
    int tid = threadIdx.x;
    int w = tid >> 6, o = tid & 63;
    const float* qgb = qg + (size_t)b * N_ * 128;
    for (int i = 0; i < 8; ++i) {
        int nl = w * 8 + i;
        int n = n0 + nl;
        float gv = qgb[(size_t)n * 128 + 64 + o];
        const int* ip = idxi + ((size_t)b * N_ + n) * K_;
        float mx = -FLT_MAX;
#pragma unroll 5
        for (int k = 0; k < K_; ++k) {
            int ik = ip[k];
            float hh = qgb[(size_t)ik * 128 + o] + gv;
            hh = (hh >= 0.f) ? hh : 0.01f * hh;
            mx = fmaxf(mx, hh);
        }
        T[nl][o] = mx;
    }
    __syncthreads();
    int ow = tid >> 2, q = tid & 3;
#pragma unroll
    for (int j4 = 0; j4 < 2; ++j4) {
        int nl = q * 8 + j4 * 4;
        float4 v;
        v.x = T[nl + 0][ow]; v.y = T[nl + 1][ow];
        v.z = T[nl + 2][ow]; v.w = T[nl + 3][ow];
        *(float4*)&out[((size_t)b * 64 + ow) * N_ + n0 + nl] = v;
    }
}

extern "C" void kernel_launch(void* const* d_in, const int* in_sizes, int n_in,
                              void* d_out, int out_size, void* d_ws, size_t ws_size,
                              hipStream_t stream) {
    const float* x = (const float*)d_in[0];
    const float* W = (const float*)d_in[1];
    float* out = (float*)d_out;

    float*          xxn  = (float*)d_ws;
    int*            idx  = (int*)((char*)d_ws + OFF_IDX);
    float*          qg   = (float*)((char*)d_ws + OFF_QG);
    u64*            bufg = (u64*)((char*)d_ws + OFF_QG);   // overlays qg (topk before qg)
    unsigned short* p0   = (unsigned short*)((char*)d_ws + OFF_P0);
    unsigned short* p1   = (unsigned short*)((char*)d_ws + OFF_P1);

    k_split<<<dim3(128), dim3(256), 0, stream>>>(x, p0, p1, xxn);
    k_topk <<<dim3(512), dim3(512), 0, stream>>>(p0, p1, xxn, bufg, idx);
    k_qg   <<<dim3(512), dim3(256), 0, stream>>>(x, W, qg);
    k_out  <<<dim3(1024), dim3(256), 0, stream>>>(qg, idx, out);
}